// Round 6
// baseline (259.656 us; speedup 1.0000x reference)
//
#include <hip/hip_runtime.h>
#include <math.h>

// ARMA GNN forward: N=100000 nodes, E=1600000 edges, 64 -> 48 -> 40.
// out = log_softmax( relu( A @ (h1@W2) + h1@V2 + b2 ) ), h1 = relu( A @ (x@W1) + x@V1 + b1 )
// A = D^-1/2 (w) D^-1/2.
// R20: binscatter write-line fix. Invariant across R14/R17/R19: ~42us
//      binscatter with WRITE_SIZE 2.6x useful bytes — per-block bin claims are
//      arbitrary-offset, so claims from different XCDs share 128B lines
//      (partial-line writeback + RFO on 8 non-coherent L2s). Now claims are
//      ROUNDED UP TO 16 EDGES (128B): every block:bin region owns whole lines.
//      Pad slots get sentinel p.x=-1 (decoded dl>=512), written densely in the
//      claim tail; build_csr skips sentinels (dl<512 guard). BIN_CAP 9216 ->
//      12288 (+34% mean padding, ~8 sigma margin). Rest identical to R19
//      (fused gemm1+binscatter, LDS-stash build_csr, csr-prefetch pulls).

constexpr int F_IN = 64;
constexpr int HIDDEN = 48;
constexpr int N_CLASS = 40;
constexpr int CHUNK = 4096;       // edges per binscatter block
constexpr int EPT = CHUNK / 256;  // 16 edges/thread, register-staged
constexpr int BIN_SHIFT = 9;      // 512 nodes per bin
constexpr int BIN_CAP = 12288;    // padded bin capacity (mean ~10900 w/ pad), 16-mult
constexpr int CSR_CAP = 12288;    // LDS stash in build_csr (>= BIN_CAP)

typedef __attribute__((ext_vector_type(8))) short bf16x8;   // 4 VGPRs
typedef __attribute__((ext_vector_type(4))) float f32x4;    // acc frag

// ---- bf16 pack helpers (RNE) ----------------------------------------------
__device__ __forceinline__ short bfr(float f) {
    unsigned u = __float_as_uint(f);
    return (short)((u + 0x7fffu + ((u >> 16) & 1u)) >> 16);
}
__device__ __forceinline__ unsigned pack_bf2(float a, float b) {
    unsigned ua = __float_as_uint(a), ub = __float_as_uint(b);
    ua = (ua + 0x7fffu + ((ua >> 16) & 1u)) >> 16;
    ub = (ub + 0x7fffu + ((ub >> 16) & 1u)) >> 16;
    return ua | (ub << 16);
}
__device__ __forceinline__ float2 unpack_bf2(unsigned u) {
    return make_float2(__uint_as_float(u << 16), __uint_as_float(u & 0xffff0000u));
}
__device__ __forceinline__ bf16x8 cvt8(float4 f0, float4 f1) {
    bf16x8 r;
    r[0] = bfr(f0.x); r[1] = bfr(f0.y); r[2] = bfr(f0.z); r[3] = bfr(f0.w);
    r[4] = bfr(f1.x); r[5] = bfr(f1.y); r[6] = bfr(f1.z); r[7] = bfr(f1.w);
    return r;
}

// ---- init: binCursor[b] = b * BIN_CAP --------------------------------------
__global__ void init_cursor(int* __restrict__ binCursor) {
    binCursor[threadIdx.x] = (int)threadIdx.x * BIN_CAP;
}

// ============================================================================
// FUSED: blocks [0,nSc) = binscatter (register-staged, 1KB LDS hist);
//        blocks [nSc,..) = MFMA layer-1 GEMM (64 nodes/block, 96 cols, K=64).
// Independent work co-resident on the CUs: scatter-bound + MFMA-bound overlap.
// ============================================================================
__global__ __launch_bounds__(256) void gemm1_binscatter(
    const float* __restrict__ X, const float* __restrict__ W,
    const float* __restrict__ V, const float* __restrict__ b,
    unsigned* __restrict__ XWp, unsigned* __restrict__ AGGp, int N,
    const int* __restrict__ src, const int* __restrict__ dst,
    const float* __restrict__ w, int* __restrict__ binCursor,
    int2* __restrict__ binned, int E, int nSc) {
    __shared__ char smem[36864];
    int tid = threadIdx.x;

    if ((int)blockIdx.x < nSc) {
        // ---- binscatter path ------------------------------------------------
        int* hist = (int*)smem;   // [256]
        hist[tid] = 0;
        __syncthreads();
        long long e0 = (long long)blockIdx.x * CHUNK;
        int M = (int)min((long long)CHUNK, (long long)E - e0);
        int dv[EPT], sv[EPT], wv[EPT];
#pragma unroll
        for (int q = 0; q < EPT; ++q) {
            int i = tid + q * 256;
            if (i < M) {
                dv[q] = dst[e0 + i];
                sv[q] = src[e0 + i];
                wv[q] = __float_as_int(w[e0 + i]);
                atomicAdd(&hist[dv[q] >> BIN_SHIFT], 1);
            }
        }
        __syncthreads();
        int h = hist[tid];
        int hp = (h + 15) & ~15;  // claim whole 128B lines (16 int2)
        int base = hp ? atomicAdd(&binCursor[tid], hp) : 0;  // line-exclusive claim
        __syncthreads();
        hist[tid] = base;  // reuse as cursor
        __syncthreads();
#pragma unroll
        for (int q = 0; q < EPT; ++q) {
            int i = tid + q * 256;
            if (i < M) {
                int d = dv[q];
                int p = atomicAdd(&hist[d >> BIN_SHIFT], 1);  // LDS cursor
                binned[p] = make_int2(((d & 511) << 17) | sv[q], wv[q]);
            }
        }
        __syncthreads();
        // tail-fill pad slots of this block's claim with sentinel (dl>=512)
        for (int j = base + h; j < base + hp; ++j)
            binned[j] = make_int2(-1, 0);
        return;
    }

    // ---- gemm1 path ---------------------------------------------------------
    short* sWT = (short*)smem;                 // [96][64]
    float* ep = (float*)(smem + 12288);        // [64][96]
    for (int i = tid; i < 96 * 64; i += 256) {
        int c = i >> 6, k = i & 63;
        float v = (c < 48) ? W[k * 48 + c] : V[k * 48 + (c - 48)];
        sWT[i] = bfr(v);
    }
    __syncthreads();

    int lane = tid & 63, wvq = tid >> 6;
    int m = lane & 15, quad = lane >> 4;
    int nb0 = ((int)blockIdx.x - nSc) * 64;
    int n = nb0 + wvq * 16 + m;

    bf16x8 a0, a1;
    if (n < N) {
        const float4* xr = (const float4*)(X + (size_t)n * 64 + quad * 8);
        a0 = cvt8(xr[0], xr[1]);
        const float4* xr2 = (const float4*)(X + (size_t)n * 64 + 32 + quad * 8);
        a1 = cvt8(xr2[0], xr2[1]);
    } else {
        for (int j = 0; j < 8; ++j) { a0[j] = 0; a1[j] = 0; }
    }

    f32x4 acc[6];
#pragma unroll
    for (int ct = 0; ct < 6; ++ct) acc[ct] = (f32x4){0.f, 0.f, 0.f, 0.f};
#pragma unroll
    for (int ct = 0; ct < 6; ++ct) {
        bf16x8 b0 = *(const bf16x8*)(sWT + (ct * 16 + m) * 64 + quad * 8);
        bf16x8 b1 = *(const bf16x8*)(sWT + (ct * 16 + m) * 64 + 32 + quad * 8);
        acc[ct] = __builtin_amdgcn_mfma_f32_16x16x32_bf16(a0, b0, acc[ct], 0, 0, 0);
        acc[ct] = __builtin_amdgcn_mfma_f32_16x16x32_bf16(a1, b1, acc[ct], 0, 0, 0);
    }
#pragma unroll
    for (int ct = 0; ct < 6; ++ct)
#pragma unroll
        for (int r = 0; r < 4; ++r)
            ep[(wvq * 16 + quad * 4 + r) * 96 + ct * 16 + m] = acc[ct][r];
    __syncthreads();
    for (int i = tid; i < 64 * 24; i += 256) {
        int r = i / 24, c2 = i - r * 24;
        int node = nb0 + r;
        if (node >= N) continue;
        float w0 = ep[r * 96 + 2 * c2], w1 = ep[r * 96 + 2 * c2 + 1];
        XWp[node * 24 + c2] = pack_bf2(w0, w1);
        float v0 = ep[r * 96 + 48 + 2 * c2], v1 = ep[r * 96 + 48 + 2 * c2 + 1];
        float2 bb = ((const float2*)b)[c2];
        AGGp[node * 24 + c2] = pack_bf2(v0 + bb.x, v1 + bb.y);
    }
}

// ---- build_csr: per-bin LDS counting sort -> compressed 4B CSR -------------
// csr[e] = (src:17 << 15) | bf15(w * dinv[dst]); writes rowBeg/rowEnd/dinv;
// epilogue scales this bin's xW1p rows by dinv (fold of old scale_xw).
// Sentinel entries (dl>=512) from padded claims are skipped.
__global__ __launch_bounds__(512) void build_csr(const int2* __restrict__ binned,
                                                 const int* __restrict__ binCursor,
                                                 int* __restrict__ rowBeg,
                                                 int* __restrict__ rowEnd,
                                                 float* __restrict__ dinv,
                                                 unsigned* __restrict__ csr,
                                                 unsigned* __restrict__ XW1p, int N) {
    __shared__ int sx[CSR_CAP];
    __shared__ int sw[CSR_CAP];
    __shared__ int cntL[512];
    __shared__ float degL[512];  // deg sums, then dinv values
    __shared__ int scanL[512];
    int b = blockIdx.x, tid = threadIdx.x;
    int e0 = b * BIN_CAP;
    int M = min(binCursor[b] - e0, BIN_CAP);  // clamp (never hit)
    cntL[tid] = 0;
    degL[tid] = 0.f;
    __syncthreads();
    for (int i = tid; i < M; i += 512) {
        int2 p = binned[e0 + i];
        sx[i] = p.x;
        sw[i] = p.y;
        unsigned dl = ((unsigned)p.x) >> 17;
        if (dl < 512u) {  // skip pad sentinels
            atomicAdd(&cntL[dl], 1);
            atomicAdd(&degL[dl], __int_as_float(p.y));
        }
    }
    __syncthreads();
    int v = cntL[tid];
    scanL[tid] = v;
    __syncthreads();
#pragma unroll
    for (int o = 1; o < 512; o <<= 1) {
        int u = (tid >= o) ? scanL[tid - o] : 0;
        __syncthreads();
        scanL[tid] += u;
        __syncthreads();
    }
    int excl = scanL[tid] - v;
    int node = (b << BIN_SHIFT) + tid;
    float dg = degL[tid];
    float dv = dg > 0.f ? rsqrtf(dg) : 0.f;
    if (node < N) {
        rowBeg[node] = e0 + excl;
        rowEnd[node] = e0 + excl + v;
        dinv[node] = dv;
    }
    cntL[tid] = e0 + excl;  // reuse as global write cursor
    degL[tid] = dv;         // reuse as dinv table
    __syncthreads();
    for (int i = tid; i < M; i += 512) {
        int px = sx[i], pw = sw[i];
        unsigned dl = ((unsigned)px) >> 17;
        if (dl >= 512u) continue;  // skip pad sentinels
        int pos = atomicAdd(&cntL[dl], 1);  // LDS atomic
        float wn = __int_as_float(pw) * degL[dl];  // fold dinv[dst] in now
        unsigned uw = __float_as_uint(wn);
        uw = (uw + 0x7fffu + ((uw >> 16) & 1u)) >> 16;  // bf16 RNE; positive -> <=0x7FFF
        csr[pos] = ((unsigned)(px & 0x1FFFF) << 15) | uw;
    }
    // ---- fold of scale_xw: scale this bin's xW1p rows by dinv (coalesced) ----
    int nb0 = b << BIN_SHIFT;
    for (int i = tid; i < 512 * 24; i += 512) {
        int nl = i / 24, c = i - nl * 24;
        int nn = nb0 + nl;
        if (nn >= N) break;
        float dvn = degL[nl];
        float2 u = unpack_bf2(XW1p[nn * 24 + c]);
        XW1p[nn * 24 + c] = pack_bf2(u.x * dvn, u.y * dvn);
    }
}

// ---- 4-edge gather+fma body (csr word already in register) -----------------
template <int W>
__device__ __forceinline__ void edge4(const unsigned* __restrict__ XWp, uint4 p4,
                                      int c, float4& s) {
    uint2 u0 = *(const uint2*)(XWp + (p4.x >> 15) * W + c);
    uint2 u1 = *(const uint2*)(XWp + (p4.y >> 15) * W + c);
    uint2 u2 = *(const uint2*)(XWp + (p4.z >> 15) * W + c);
    uint2 u3 = *(const uint2*)(XWp + (p4.w >> 15) * W + c);
    float n0 = __uint_as_float((p4.x & 0x7FFFu) << 16);
    float n1 = __uint_as_float((p4.y & 0x7FFFu) << 16);
    float n2 = __uint_as_float((p4.z & 0x7FFFu) << 16);
    float n3 = __uint_as_float((p4.w & 0x7FFFu) << 16);
    float2 a0 = unpack_bf2(u0.x), b0 = unpack_bf2(u0.y);
    float2 a1 = unpack_bf2(u1.x), b1 = unpack_bf2(u1.y);
    float2 a2 = unpack_bf2(u2.x), b2 = unpack_bf2(u2.y);
    float2 a3 = unpack_bf2(u3.x), b3 = unpack_bf2(u3.y);
    s.x = fmaf(a0.x, n0, s.x); s.y = fmaf(a0.y, n0, s.y);
    s.z = fmaf(b0.x, n0, s.z); s.w = fmaf(b0.y, n0, s.w);
    s.x = fmaf(a1.x, n1, s.x); s.y = fmaf(a1.y, n1, s.y);
    s.z = fmaf(b1.x, n1, s.z); s.w = fmaf(b1.y, n1, s.w);
    s.x = fmaf(a2.x, n2, s.x); s.y = fmaf(a2.y, n2, s.y);
    s.z = fmaf(b2.x, n2, s.z); s.w = fmaf(b2.y, n2, s.w);
    s.x = fmaf(a3.x, n3, s.x); s.y = fmaf(a3.y, n3, s.y);
    s.z = fmaf(b3.x, n3, s.z); s.w = fmaf(b3.y, n3, s.w);
}

// ---- row accumulate: 2 u32 cols/thread, aligned uint4 csr loads, 1-deep
//      csr prefetch (next chunk's uint4 issued before this chunk's gathers;
//      it is older in vmcnt order so the gather waitcnt drains it for free).
template <int W>
__device__ __forceinline__ float4 row_accum2(const unsigned* __restrict__ XWp,
                                             const unsigned* __restrict__ csr,
                                             int j, int end, int c, float4 s) {
    // head: scalar until j is 4-aligned
    while (j < end && (j & 3)) {
        unsigned p = csr[j++];
        uint2 u = *(const uint2*)(XWp + (p >> 15) * W + c);
        float nr = __uint_as_float((p & 0x7FFFu) << 16);
        float2 x0 = unpack_bf2(u.x), x1 = unpack_bf2(u.y);
        s.x = fmaf(x0.x, nr, s.x); s.y = fmaf(x0.y, nr, s.y);
        s.z = fmaf(x1.x, nr, s.z); s.w = fmaf(x1.y, nr, s.w);
    }
    int nch = (end - j) >> 2;
    if (nch > 0) {
        uint4 p4 = *(const uint4*)(csr + j);
        for (int k = 1; k < nch; ++k) {
            uint4 p4n = *(const uint4*)(csr + j + (k << 2));  // prefetch next chunk
            edge4<W>(XWp, p4, c, s);
            p4 = p4n;
        }
        edge4<W>(XWp, p4, c, s);
        j += nch << 2;
    }
    for (; j < end; ++j) {
        unsigned p = csr[j];
        uint2 u = *(const uint2*)(XWp + (p >> 15) * W + c);
        float nr = __uint_as_float((p & 0x7FFFu) << 16);
        float2 x0 = unpack_bf2(u.x), x1 = unpack_bf2(u.y);
        s.x = fmaf(x0.x, nr, s.x); s.y = fmaf(x0.y, nr, s.y);
        s.z = fmaf(x1.x, nr, s.z); s.w = fmaf(x1.y, nr, s.w);
    }
    return s;
}

// ---- layer-1 pull: h1[n] = relu(bf16(AGG1p[n]) + sum_j xWp[src_j]*nrm_j) ---
// 12 threads/node, 2 u32 cols each; block 384 = 32 nodes. Skinny: 0 LDS.
__global__ __launch_bounds__(384) void pull_agg(const unsigned* __restrict__ XWp,
                                                const unsigned* __restrict__ csr,
                                                const int* __restrict__ rowBeg,
                                                const int* __restrict__ rowEnd,
                                                const unsigned* __restrict__ AGG1p,
                                                unsigned* __restrict__ H1p, int N) {
    int t = blockIdx.x * blockDim.x + threadIdx.x;
    int n = t / 12, c1 = t - n * 12;
    if (n >= N) return;
    int c = 2 * c1;
    uint2 a = *(const uint2*)(AGG1p + n * 24 + c);
    float2 f0 = unpack_bf2(a.x), f1 = unpack_bf2(a.y);
    float4 s = make_float4(f0.x, f0.y, f1.x, f1.y);
    s = row_accum2<24>(XWp, csr, rowBeg[n], rowEnd[n], c, s);
    uint2 o;
    o.x = pack_bf2(fmaxf(s.x, 0.f), fmaxf(s.y, 0.f));
    o.y = pack_bf2(fmaxf(s.z, 0.f), fmaxf(s.w, 0.f));
    *(uint2*)(H1p + n * 24 + c) = o;  // relu'd bf16 h1
}

// ============================================================================
// MFMA layer-2 GEMM: 64 nodes/block, 80 cols (W2|V2), K=48 zero-padded to 64.
// ============================================================================
__global__ __launch_bounds__(256) void gemm2_kernel(
    const short* __restrict__ H1, const float* __restrict__ W,
    const float* __restrict__ V, const float* __restrict__ b,
    const float* __restrict__ dinv, unsigned* __restrict__ XWp,
    unsigned* __restrict__ AGGp, int N) {
    __shared__ char smem[30720];
    short* sWT = (short*)smem;            // [80][64], k>=48 zero
    float* ep = (float*)(smem + 10240);   // [64][80]
    int tid = threadIdx.x;
    for (int i = tid; i < 80 * 64; i += 256) {
        int c = i >> 6, k = i & 63;
        float v = 0.f;
        if (k < 48) v = (c < 40) ? W[k * 40 + c] : V[k * 40 + (c - 40)];
        sWT[i] = bfr(v);
    }
    __syncthreads();

    int lane = tid & 63, wv = tid >> 6;
    int m = lane & 15, quad = lane >> 4;
    int nb0 = (int)blockIdx.x * 64;
    int n = nb0 + wv * 16 + m;

    bf16x8 a0, a1;
    if (n < N) {
        a0 = *(const bf16x8*)(H1 + (size_t)n * 48 + quad * 8);
        if (quad < 2) {
            a1 = *(const bf16x8*)(H1 + (size_t)n * 48 + 32 + quad * 8);
        } else {
            for (int j = 0; j < 8; ++j) a1[j] = 0;
        }
    } else {
        for (int j = 0; j < 8; ++j) { a0[j] = 0; a1[j] = 0; }
    }

    f32x4 acc[5];
#pragma unroll
    for (int ct = 0; ct < 5; ++ct) acc[ct] = (f32x4){0.f, 0.f, 0.f, 0.f};
#pragma unroll
    for (int ct = 0; ct < 5; ++ct) {
        bf16x8 b0 = *(const bf16x8*)(sWT + (ct * 16 + m) * 64 + quad * 8);
        bf16x8 b1 = *(const bf16x8*)(sWT + (ct * 16 + m) * 64 + 32 + quad * 8);
        acc[ct] = __builtin_amdgcn_mfma_f32_16x16x32_bf16(a0, b0, acc[ct], 0, 0, 0);
        acc[ct] = __builtin_amdgcn_mfma_f32_16x16x32_bf16(a1, b1, acc[ct], 0, 0, 0);
    }
#pragma unroll
    for (int ct = 0; ct < 5; ++ct)
#pragma unroll
        for (int r = 0; r < 4; ++r)
            ep[(wv * 16 + quad * 4 + r) * 80 + ct * 16 + m] = acc[ct][r];
    __syncthreads();
    for (int i = tid; i < 64 * 20; i += 256) {
        int r = i / 20, c2 = i - r * 20;
        int node = nb0 + r;
        if (node >= N) continue;
        float dv = dinv[node];
        float w0 = ep[r * 80 + 2 * c2], w1 = ep[r * 80 + 2 * c2 + 1];
        XWp[node * 20 + c2] = pack_bf2(w0 * dv, w1 * dv);
        float v0 = ep[r * 80 + 40 + 2 * c2], v1 = ep[r * 80 + 40 + 2 * c2 + 1];
        float2 bb = ((const float2*)b)[c2];
        AGGp[node * 20 + c2] = pack_bf2(v0 + bb.x, v1 + bb.y);
    }
}

// ---- layer-2 pull fused with log_softmax(relu(.)) --------------------------
// block = 320 threads = 32 nodes x 10 threads (2 u32 cols each).
__global__ __launch_bounds__(320) void pull_ls(const unsigned* __restrict__ XWp,
                                               const unsigned* __restrict__ csr,
                                               const int* __restrict__ rowBeg,
                                               const int* __restrict__ rowEnd,
                                               const unsigned* __restrict__ AGG2p,
                                               float* __restrict__ out, int N) {
    __shared__ float4 sbuf[32 * 10];
    __shared__ float sl[32];
    int tid = threadIdx.x;
    int nl = tid / 10, c1 = tid - nl * 10;
    int n = blockIdx.x * 32 + nl;
    int c = 2 * c1;
    float4 s = make_float4(0.f, 0.f, 0.f, 0.f);
    if (n < N) {
        uint2 a = *(const uint2*)(AGG2p + n * 20 + c);
        float2 f0 = unpack_bf2(a.x), f1 = unpack_bf2(a.y);
        s = make_float4(f0.x, f0.y, f1.x, f1.y);
        s = row_accum2<20>(XWp, csr, rowBeg[n], rowEnd[n], c, s);
    }
    sbuf[nl * 10 + c1] = s;
    __syncthreads();
    if (tid < 32) {
        float m = 0.f;  // relu floor
        for (int k = 0; k < 10; ++k) {
            float4 v = sbuf[tid * 10 + k];
            m = fmaxf(m, fmaxf(fmaxf(v.x, v.y), fmaxf(v.z, v.w)));
        }
        float sum = 0.f;
        for (int k = 0; k < 10; ++k) {
            float4 v = sbuf[tid * 10 + k];
            sum += expf(fmaxf(v.x, 0.f) - m) + expf(fmaxf(v.y, 0.f) - m) +
                   expf(fmaxf(v.z, 0.f) - m) + expf(fmaxf(v.w, 0.f) - m);
        }
        sl[tid] = m + logf(sum);
    }
    __syncthreads();
    if (n < N) {
        float l = sl[nl];
        ((float4*)out)[n * 10 + c1] =
            make_float4(fmaxf(s.x, 0.f) - l, fmaxf(s.y, 0.f) - l,
                        fmaxf(s.z, 0.f) - l, fmaxf(s.w, 0.f) - l);
    }
}

extern "C" void kernel_launch(void* const* d_in, const int* in_sizes, int n_in,
                              void* d_out, int out_size, void* d_ws, size_t ws_size,
                              hipStream_t stream) {
    const float* x  = (const float*)d_in[0];
    const int*   ei = (const int*)d_in[1];
    const float* ew = (const float*)d_in[2];
    const float* W1 = (const float*)d_in[3];
    const float* V1 = (const float*)d_in[4];
    const float* b1 = (const float*)d_in[5];
    const float* W2 = (const float*)d_in[6];
    const float* V2 = (const float*)d_in[7];
    const float* b2 = (const float*)d_in[8];
    float* out = (float*)d_out;

    const int N = in_sizes[0] / F_IN;
    const int E = in_sizes[2];
    const int* src = ei;
    const int* dst = ei + E;

    char* ws = (char*)d_ws;
    size_t off = 0;
    auto carve = [&](size_t bytes) {
        void* p = ws + off;
        off = (off + bytes + 255) & ~size_t(255);
        return p;
    };
    int*      binCursor = (int*)carve(256 * 4);
    int*      rowBeg    = (int*)carve((size_t)N * 4);
    int*      rowEnd    = (int*)carve((size_t)N * 4);
    float*    dinv      = (float*)carve((size_t)N * 4);
    int2*     binned    = (int2*)carve((size_t)256 * BIN_CAP * 8);
    unsigned* csr       = (unsigned*)carve((size_t)256 * BIN_CAP * 4);
    unsigned* xW1p      = (unsigned*)carve((size_t)N * 24 * 4);   // bf16x2 flat
    unsigned* agg1p     = (unsigned*)carve((size_t)N * 24 * 4);   // bf16x2 V1-part
    unsigned* h1p       = (unsigned*)carve((size_t)N * 24 * 4);   // relu'd bf16 h1
    unsigned* xW2p      = (unsigned*)carve((size_t)N * 20 * 4);
    unsigned* agg2p     = (unsigned*)carve((size_t)N * 20 * 4);   // bf16x2 V2-part

    const int B = 256;
    auto cdiv = [](long long a, long long b) { return (int)((a + b - 1) / b); };
    const int nSc = cdiv(E, CHUNK);
    const int nBins = (N + (1 << BIN_SHIFT) - 1) >> BIN_SHIFT;
    const int nGemmBlocks = cdiv(N, 64);

    init_cursor<<<1, 256, 0, stream>>>(binCursor);
    gemm1_binscatter<<<nSc + nGemmBlocks, B, 0, stream>>>(
        x, W1, V1, b1, xW1p, agg1p, N, src, dst, ew, binCursor, binned, E, nSc);
    build_csr<<<nBins, 512, 0, stream>>>(binned, binCursor, rowBeg, rowEnd,
                                         dinv, csr, xW1p, N);

    pull_agg<<<cdiv((long long)N * 12, 384), 384, 0, stream>>>(xW1p, csr, rowBeg,
                                                               rowEnd, agg1p, h1p, N);

    gemm2_kernel<<<nGemmBlocks, B, 0, stream>>>((const short*)h1p, W2, V2, b2,
                                                dinv, xW2p, agg2p, N);

    pull_ls<<<cdiv(N, 32), 320, 0, stream>>>(xW2p, csr, rowBeg, rowEnd,
                                             agg2p, out, N);
}

// Round 7
// 257.948 us; speedup vs baseline: 1.0066x; 1.0066x over previous
//
#include <hip/hip_runtime.h>
#include <math.h>

// ARMA GNN forward: N=100000 nodes, E=1600000 edges, 64 -> 48 -> 40.
// out = log_softmax( relu( A @ (h1@W2) + h1@V2 + b2 ) ), h1 = relu( A @ (x@W1) + x@V1 + b1 )
// A = D^-1/2 (w) D^-1/2.
// R21: R20's line-padded claims REVERTED (WRITE_SIZE rose by exactly the pad
//      volume — amplification is not line-sharing; binscatter is plateaued at
//      ~42us across 3 structures, leave it fused with gemm1). Build chain =
//      R19 exact. NEW: 2-deep software pipeline in row_accum2 — hold csr
//      chunks pa,pb and one gather set in flight; each iter prefetches csr
//      k+2, issues gathers for k+1 (from pb, in-register), FMAs chunk k.
//      Gather round-trip hides under the previous chunk's work instead of
//      serializing. Named registers only (no runtime-indexed arrays).

constexpr int F_IN = 64;
constexpr int HIDDEN = 48;
constexpr int N_CLASS = 40;
constexpr int CHUNK = 4096;       // edges per binscatter block
constexpr int EPT = CHUNK / 256;  // 16 edges/thread, register-staged
constexpr int BIN_SHIFT = 9;      // 512 nodes per bin
constexpr int BIN_CAP = 9216;     // padded bin capacity (mean 8163, sigma ~79)
constexpr int CSR_CAP = 12288;    // LDS stash in build_csr (>= BIN_CAP)

typedef __attribute__((ext_vector_type(8))) short bf16x8;   // 4 VGPRs
typedef __attribute__((ext_vector_type(4))) float f32x4;    // acc frag

// ---- bf16 pack helpers (RNE) ----------------------------------------------
__device__ __forceinline__ short bfr(float f) {
    unsigned u = __float_as_uint(f);
    return (short)((u + 0x7fffu + ((u >> 16) & 1u)) >> 16);
}
__device__ __forceinline__ unsigned pack_bf2(float a, float b) {
    unsigned ua = __float_as_uint(a), ub = __float_as_uint(b);
    ua = (ua + 0x7fffu + ((ua >> 16) & 1u)) >> 16;
    ub = (ub + 0x7fffu + ((ub >> 16) & 1u)) >> 16;
    return ua | (ub << 16);
}
__device__ __forceinline__ float2 unpack_bf2(unsigned u) {
    return make_float2(__uint_as_float(u << 16), __uint_as_float(u & 0xffff0000u));
}
__device__ __forceinline__ bf16x8 cvt8(float4 f0, float4 f1) {
    bf16x8 r;
    r[0] = bfr(f0.x); r[1] = bfr(f0.y); r[2] = bfr(f0.z); r[3] = bfr(f0.w);
    r[4] = bfr(f1.x); r[5] = bfr(f1.y); r[6] = bfr(f1.z); r[7] = bfr(f1.w);
    return r;
}

// ---- init: binCursor[b] = b * BIN_CAP --------------------------------------
__global__ void init_cursor(int* __restrict__ binCursor) {
    binCursor[threadIdx.x] = (int)threadIdx.x * BIN_CAP;
}

// ============================================================================
// FUSED: blocks [0,nSc) = binscatter (register-staged, 1KB LDS hist);
//        blocks [nSc,..) = MFMA layer-1 GEMM (64 nodes/block, 96 cols, K=64).
// ============================================================================
__global__ __launch_bounds__(256) void gemm1_binscatter(
    const float* __restrict__ X, const float* __restrict__ W,
    const float* __restrict__ V, const float* __restrict__ b,
    unsigned* __restrict__ XWp, unsigned* __restrict__ AGGp, int N,
    const int* __restrict__ src, const int* __restrict__ dst,
    const float* __restrict__ w, int* __restrict__ binCursor,
    int2* __restrict__ binned, int E, int nSc) {
    __shared__ char smem[36864];
    int tid = threadIdx.x;

    if ((int)blockIdx.x < nSc) {
        // ---- binscatter path ------------------------------------------------
        int* hist = (int*)smem;   // [256]
        hist[tid] = 0;
        __syncthreads();
        long long e0 = (long long)blockIdx.x * CHUNK;
        int M = (int)min((long long)CHUNK, (long long)E - e0);
        int dv[EPT], sv[EPT], wv[EPT];
#pragma unroll
        for (int q = 0; q < EPT; ++q) {
            int i = tid + q * 256;
            if (i < M) {
                dv[q] = dst[e0 + i];
                sv[q] = src[e0 + i];
                wv[q] = __float_as_int(w[e0 + i]);
                atomicAdd(&hist[dv[q] >> BIN_SHIFT], 1);
            }
        }
        __syncthreads();
        int h = hist[tid];
        int base = h ? atomicAdd(&binCursor[tid], h) : 0;  // global range claim
        __syncthreads();
        hist[tid] = base;  // reuse as cursor
        __syncthreads();
#pragma unroll
        for (int q = 0; q < EPT; ++q) {
            int i = tid + q * 256;
            if (i < M) {
                int d = dv[q];
                int p = atomicAdd(&hist[d >> BIN_SHIFT], 1);  // LDS cursor
                binned[p] = make_int2(((d & 511) << 17) | sv[q], wv[q]);
            }
        }
        return;
    }

    // ---- gemm1 path ---------------------------------------------------------
    short* sWT = (short*)smem;                 // [96][64]
    float* ep = (float*)(smem + 12288);        // [64][96]
    for (int i = tid; i < 96 * 64; i += 256) {
        int c = i >> 6, k = i & 63;
        float v = (c < 48) ? W[k * 48 + c] : V[k * 48 + (c - 48)];
        sWT[i] = bfr(v);
    }
    __syncthreads();

    int lane = tid & 63, wvq = tid >> 6;
    int m = lane & 15, quad = lane >> 4;
    int nb0 = ((int)blockIdx.x - nSc) * 64;
    int n = nb0 + wvq * 16 + m;

    bf16x8 a0, a1;
    if (n < N) {
        const float4* xr = (const float4*)(X + (size_t)n * 64 + quad * 8);
        a0 = cvt8(xr[0], xr[1]);
        const float4* xr2 = (const float4*)(X + (size_t)n * 64 + 32 + quad * 8);
        a1 = cvt8(xr2[0], xr2[1]);
    } else {
        for (int j = 0; j < 8; ++j) { a0[j] = 0; a1[j] = 0; }
    }

    f32x4 acc[6];
#pragma unroll
    for (int ct = 0; ct < 6; ++ct) acc[ct] = (f32x4){0.f, 0.f, 0.f, 0.f};
#pragma unroll
    for (int ct = 0; ct < 6; ++ct) {
        bf16x8 b0 = *(const bf16x8*)(sWT + (ct * 16 + m) * 64 + quad * 8);
        bf16x8 b1 = *(const bf16x8*)(sWT + (ct * 16 + m) * 64 + 32 + quad * 8);
        acc[ct] = __builtin_amdgcn_mfma_f32_16x16x32_bf16(a0, b0, acc[ct], 0, 0, 0);
        acc[ct] = __builtin_amdgcn_mfma_f32_16x16x32_bf16(a1, b1, acc[ct], 0, 0, 0);
    }
#pragma unroll
    for (int ct = 0; ct < 6; ++ct)
#pragma unroll
        for (int r = 0; r < 4; ++r)
            ep[(wvq * 16 + quad * 4 + r) * 96 + ct * 16 + m] = acc[ct][r];
    __syncthreads();
    for (int i = tid; i < 64 * 24; i += 256) {
        int r = i / 24, c2 = i - r * 24;
        int node = nb0 + r;
        if (node >= N) continue;
        float w0 = ep[r * 96 + 2 * c2], w1 = ep[r * 96 + 2 * c2 + 1];
        XWp[node * 24 + c2] = pack_bf2(w0, w1);
        float v0 = ep[r * 96 + 48 + 2 * c2], v1 = ep[r * 96 + 48 + 2 * c2 + 1];
        float2 bb = ((const float2*)b)[c2];
        AGGp[node * 24 + c2] = pack_bf2(v0 + bb.x, v1 + bb.y);
    }
}

// ---- build_csr: per-bin LDS counting sort -> compressed 4B CSR -------------
__global__ __launch_bounds__(512) void build_csr(const int2* __restrict__ binned,
                                                 const int* __restrict__ binCursor,
                                                 int* __restrict__ rowBeg,
                                                 int* __restrict__ rowEnd,
                                                 float* __restrict__ dinv,
                                                 unsigned* __restrict__ csr,
                                                 unsigned* __restrict__ XW1p, int N) {
    __shared__ int sx[CSR_CAP];
    __shared__ int sw[CSR_CAP];
    __shared__ int cntL[512];
    __shared__ float degL[512];  // deg sums, then dinv values
    __shared__ int scanL[512];
    int b = blockIdx.x, tid = threadIdx.x;
    int e0 = b * BIN_CAP;
    int M = min(binCursor[b] - e0, BIN_CAP);  // clamp (never hit)
    cntL[tid] = 0;
    degL[tid] = 0.f;
    __syncthreads();
    for (int i = tid; i < M; i += 512) {
        int2 p = binned[e0 + i];
        sx[i] = p.x;
        sw[i] = p.y;
        int dl = ((unsigned)p.x) >> 17;
        atomicAdd(&cntL[dl], 1);
        atomicAdd(&degL[dl], __int_as_float(p.y));
    }
    __syncthreads();
    int v = cntL[tid];
    scanL[tid] = v;
    __syncthreads();
#pragma unroll
    for (int o = 1; o < 512; o <<= 1) {
        int u = (tid >= o) ? scanL[tid - o] : 0;
        __syncthreads();
        scanL[tid] += u;
        __syncthreads();
    }
    int excl = scanL[tid] - v;
    int node = (b << BIN_SHIFT) + tid;
    float dg = degL[tid];
    float dv = dg > 0.f ? rsqrtf(dg) : 0.f;
    if (node < N) {
        rowBeg[node] = e0 + excl;
        rowEnd[node] = e0 + excl + v;
        dinv[node] = dv;
    }
    cntL[tid] = e0 + excl;  // reuse as global write cursor
    degL[tid] = dv;         // reuse as dinv table
    __syncthreads();
    for (int i = tid; i < M; i += 512) {
        int px = sx[i], pw = sw[i];
        int dl = ((unsigned)px) >> 17;
        int pos = atomicAdd(&cntL[dl], 1);  // LDS atomic
        float wn = __int_as_float(pw) * degL[dl];  // fold dinv[dst] in now
        unsigned uw = __float_as_uint(wn);
        uw = (uw + 0x7fffu + ((uw >> 16) & 1u)) >> 16;  // bf16 RNE; positive -> <=0x7FFF
        csr[pos] = ((unsigned)(px & 0x1FFFF) << 15) | uw;
    }
    // ---- fold of scale_xw: scale this bin's xW1p rows by dinv (coalesced) ----
    int nb0 = b << BIN_SHIFT;
    for (int i = tid; i < 512 * 24; i += 512) {
        int nl = i / 24, c = i - nl * 24;
        int nn = nb0 + nl;
        if (nn >= N) break;
        float dvn = degL[nl];
        float2 u = unpack_bf2(XW1p[nn * 24 + c]);
        XW1p[nn * 24 + c] = pack_bf2(u.x * dvn, u.y * dvn);
    }
}

// ---- 4-edge FMA body: csr word AND its 4 gathered uint2 already in regs ----
__device__ __forceinline__ void fma4(uint4 p4, uint2 u0, uint2 u1, uint2 u2,
                                     uint2 u3, float4& s) {
    float n0 = __uint_as_float((p4.x & 0x7FFFu) << 16);
    float n1 = __uint_as_float((p4.y & 0x7FFFu) << 16);
    float n2 = __uint_as_float((p4.z & 0x7FFFu) << 16);
    float n3 = __uint_as_float((p4.w & 0x7FFFu) << 16);
    float2 a0 = unpack_bf2(u0.x), b0 = unpack_bf2(u0.y);
    float2 a1 = unpack_bf2(u1.x), b1 = unpack_bf2(u1.y);
    float2 a2 = unpack_bf2(u2.x), b2 = unpack_bf2(u2.y);
    float2 a3 = unpack_bf2(u3.x), b3 = unpack_bf2(u3.y);
    s.x = fmaf(a0.x, n0, s.x); s.y = fmaf(a0.y, n0, s.y);
    s.z = fmaf(b0.x, n0, s.z); s.w = fmaf(b0.y, n0, s.w);
    s.x = fmaf(a1.x, n1, s.x); s.y = fmaf(a1.y, n1, s.y);
    s.z = fmaf(b1.x, n1, s.z); s.w = fmaf(b1.y, n1, s.w);
    s.x = fmaf(a2.x, n2, s.x); s.y = fmaf(a2.y, n2, s.y);
    s.z = fmaf(b2.x, n2, s.z); s.w = fmaf(b2.y, n2, s.w);
    s.x = fmaf(a3.x, n3, s.x); s.y = fmaf(a3.y, n3, s.y);
    s.z = fmaf(b3.x, n3, s.z); s.w = fmaf(b3.y, n3, s.w);
}

// ---- row accumulate: 2-deep software pipeline ------------------------------
// Holds csr chunks pa,pb and one gather set in flight. Iter k: prefetch csr
// k+2; issue gathers for k+1 (addresses from pb, in-register); FMA chunk k
// (gathers issued last iter). Gather round-trip hides under previous chunk.
template <int W>
__device__ __forceinline__ float4 row_accum2(const unsigned* __restrict__ XWp,
                                             const unsigned* __restrict__ csr,
                                             int j, int end, int c, float4 s) {
    // head: scalar until j is 4-aligned (bin bases are 4-edge aligned)
    while (j < end && (j & 3)) {
        unsigned p = csr[j++];
        uint2 u = *(const uint2*)(XWp + (p >> 15) * W + c);
        float nr = __uint_as_float((p & 0x7FFFu) << 16);
        float2 x0 = unpack_bf2(u.x), x1 = unpack_bf2(u.y);
        s.x = fmaf(x0.x, nr, s.x); s.y = fmaf(x0.y, nr, s.y);
        s.z = fmaf(x1.x, nr, s.z); s.w = fmaf(x1.y, nr, s.w);
    }
    int nch = (end - j) >> 2;
    const uint4* cp = (const uint4*)(csr + j);
    if (nch >= 2) {
        uint4 pa = cp[0];
        uint4 pb = cp[1];
        uint2 g0 = *(const uint2*)(XWp + (pa.x >> 15) * W + c);
        uint2 g1 = *(const uint2*)(XWp + (pa.y >> 15) * W + c);
        uint2 g2 = *(const uint2*)(XWp + (pa.z >> 15) * W + c);
        uint2 g3 = *(const uint2*)(XWp + (pa.w >> 15) * W + c);
        for (int k = 0; k + 2 < nch; ++k) {
            uint4 pc = cp[k + 2];  // csr prefetch (2 ahead)
            uint2 h0 = *(const uint2*)(XWp + (pb.x >> 15) * W + c);
            uint2 h1 = *(const uint2*)(XWp + (pb.y >> 15) * W + c);
            uint2 h2 = *(const uint2*)(XWp + (pb.z >> 15) * W + c);
            uint2 h3 = *(const uint2*)(XWp + (pb.w >> 15) * W + c);
            fma4(pa, g0, g1, g2, g3, s);   // waits only on g*, h*/pc stay in flight
            pa = pb; pb = pc;
            g0 = h0; g1 = h1; g2 = h2; g3 = h3;
        }
        // two chunks remain: pa (gathers in g*), pb (csr only)
        uint2 h0 = *(const uint2*)(XWp + (pb.x >> 15) * W + c);
        uint2 h1 = *(const uint2*)(XWp + (pb.y >> 15) * W + c);
        uint2 h2 = *(const uint2*)(XWp + (pb.z >> 15) * W + c);
        uint2 h3 = *(const uint2*)(XWp + (pb.w >> 15) * W + c);
        fma4(pa, g0, g1, g2, g3, s);
        fma4(pb, h0, h1, h2, h3, s);
        j += nch << 2;
    } else if (nch == 1) {
        uint4 pa = cp[0];
        uint2 g0 = *(const uint2*)(XWp + (pa.x >> 15) * W + c);
        uint2 g1 = *(const uint2*)(XWp + (pa.y >> 15) * W + c);
        uint2 g2 = *(const uint2*)(XWp + (pa.z >> 15) * W + c);
        uint2 g3 = *(const uint2*)(XWp + (pa.w >> 15) * W + c);
        fma4(pa, g0, g1, g2, g3, s);
        j += 4;
    }
    for (; j < end; ++j) {
        unsigned p = csr[j];
        uint2 u = *(const uint2*)(XWp + (p >> 15) * W + c);
        float nr = __uint_as_float((p & 0x7FFFu) << 16);
        float2 x0 = unpack_bf2(u.x), x1 = unpack_bf2(u.y);
        s.x = fmaf(x0.x, nr, s.x); s.y = fmaf(x0.y, nr, s.y);
        s.z = fmaf(x1.x, nr, s.z); s.w = fmaf(x1.y, nr, s.w);
    }
    return s;
}

// ---- layer-1 pull: h1[n] = relu(bf16(AGG1p[n]) + sum_j xWp[src_j]*nrm_j) ---
// 12 threads/node, 2 u32 cols each; block 384 = 32 nodes. Skinny: 0 LDS.
__global__ __launch_bounds__(384) void pull_agg(const unsigned* __restrict__ XWp,
                                                const unsigned* __restrict__ csr,
                                                const int* __restrict__ rowBeg,
                                                const int* __restrict__ rowEnd,
                                                const unsigned* __restrict__ AGG1p,
                                                unsigned* __restrict__ H1p, int N) {
    int t = blockIdx.x * blockDim.x + threadIdx.x;
    int n = t / 12, c1 = t - n * 12;
    if (n >= N) return;
    int c = 2 * c1;
    uint2 a = *(const uint2*)(AGG1p + n * 24 + c);
    float2 f0 = unpack_bf2(a.x), f1 = unpack_bf2(a.y);
    float4 s = make_float4(f0.x, f0.y, f1.x, f1.y);
    s = row_accum2<24>(XWp, csr, rowBeg[n], rowEnd[n], c, s);
    uint2 o;
    o.x = pack_bf2(fmaxf(s.x, 0.f), fmaxf(s.y, 0.f));
    o.y = pack_bf2(fmaxf(s.z, 0.f), fmaxf(s.w, 0.f));
    *(uint2*)(H1p + n * 24 + c) = o;  // relu'd bf16 h1
}

// ============================================================================
// MFMA layer-2 GEMM: 64 nodes/block, 80 cols (W2|V2), K=48 zero-padded to 64.
// ============================================================================
__global__ __launch_bounds__(256) void gemm2_kernel(
    const short* __restrict__ H1, const float* __restrict__ W,
    const float* __restrict__ V, const float* __restrict__ b,
    const float* __restrict__ dinv, unsigned* __restrict__ XWp,
    unsigned* __restrict__ AGGp, int N) {
    __shared__ char smem[30720];
    short* sWT = (short*)smem;            // [80][64], k>=48 zero
    float* ep = (float*)(smem + 10240);   // [64][80]
    int tid = threadIdx.x;
    for (int i = tid; i < 80 * 64; i += 256) {
        int c = i >> 6, k = i & 63;
        float v = 0.f;
        if (k < 48) v = (c < 40) ? W[k * 40 + c] : V[k * 40 + (c - 40)];
        sWT[i] = bfr(v);
    }
    __syncthreads();

    int lane = tid & 63, wv = tid >> 6;
    int m = lane & 15, quad = lane >> 4;
    int nb0 = (int)blockIdx.x * 64;
    int n = nb0 + wv * 16 + m;

    bf16x8 a0, a1;
    if (n < N) {
        a0 = *(const bf16x8*)(H1 + (size_t)n * 48 + quad * 8);
        if (quad < 2) {
            a1 = *(const bf16x8*)(H1 + (size_t)n * 48 + 32 + quad * 8);
        } else {
            for (int j = 0; j < 8; ++j) a1[j] = 0;
        }
    } else {
        for (int j = 0; j < 8; ++j) { a0[j] = 0; a1[j] = 0; }
    }

    f32x4 acc[5];
#pragma unroll
    for (int ct = 0; ct < 5; ++ct) acc[ct] = (f32x4){0.f, 0.f, 0.f, 0.f};
#pragma unroll
    for (int ct = 0; ct < 5; ++ct) {
        bf16x8 b0 = *(const bf16x8*)(sWT + (ct * 16 + m) * 64 + quad * 8);
        bf16x8 b1 = *(const bf16x8*)(sWT + (ct * 16 + m) * 64 + 32 + quad * 8);
        acc[ct] = __builtin_amdgcn_mfma_f32_16x16x32_bf16(a0, b0, acc[ct], 0, 0, 0);
        acc[ct] = __builtin_amdgcn_mfma_f32_16x16x32_bf16(a1, b1, acc[ct], 0, 0, 0);
    }
#pragma unroll
    for (int ct = 0; ct < 5; ++ct)
#pragma unroll
        for (int r = 0; r < 4; ++r)
            ep[(wv * 16 + quad * 4 + r) * 80 + ct * 16 + m] = acc[ct][r];
    __syncthreads();
    for (int i = tid; i < 64 * 20; i += 256) {
        int r = i / 20, c2 = i - r * 20;
        int node = nb0 + r;
        if (node >= N) continue;
        float dv = dinv[node];
        float w0 = ep[r * 80 + 2 * c2], w1 = ep[r * 80 + 2 * c2 + 1];
        XWp[node * 20 + c2] = pack_bf2(w0 * dv, w1 * dv);
        float v0 = ep[r * 80 + 40 + 2 * c2], v1 = ep[r * 80 + 40 + 2 * c2 + 1];
        float2 bb = ((const float2*)b)[c2];
        AGGp[node * 20 + c2] = pack_bf2(v0 + bb.x, v1 + bb.y);
    }
}

// ---- layer-2 pull fused with log_softmax(relu(.)) --------------------------
// block = 320 threads = 32 nodes x 10 threads (2 u32 cols each).
__global__ __launch_bounds__(320) void pull_ls(const unsigned* __restrict__ XWp,
                                               const unsigned* __restrict__ csr,
                                               const int* __restrict__ rowBeg,
                                               const int* __restrict__ rowEnd,
                                               const unsigned* __restrict__ AGG2p,
                                               float* __restrict__ out, int N) {
    __shared__ float4 sbuf[32 * 10];
    __shared__ float sl[32];
    int tid = threadIdx.x;
    int nl = tid / 10, c1 = tid - nl * 10;
    int n = blockIdx.x * 32 + nl;
    int c = 2 * c1;
    float4 s = make_float4(0.f, 0.f, 0.f, 0.f);
    if (n < N) {
        uint2 a = *(const uint2*)(AGG2p + n * 20 + c);
        float2 f0 = unpack_bf2(a.x), f1 = unpack_bf2(a.y);
        s = make_float4(f0.x, f0.y, f1.x, f1.y);
        s = row_accum2<20>(XWp, csr, rowBeg[n], rowEnd[n], c, s);
    }
    sbuf[nl * 10 + c1] = s;
    __syncthreads();
    if (tid < 32) {
        float m = 0.f;  // relu floor
        for (int k = 0; k < 10; ++k) {
            float4 v = sbuf[tid * 10 + k];
            m = fmaxf(m, fmaxf(fmaxf(v.x, v.y), fmaxf(v.z, v.w)));
        }
        float sum = 0.f;
        for (int k = 0; k < 10; ++k) {
            float4 v = sbuf[tid * 10 + k];
            sum += expf(fmaxf(v.x, 0.f) - m) + expf(fmaxf(v.y, 0.f) - m) +
                   expf(fmaxf(v.z, 0.f) - m) + expf(fmaxf(v.w, 0.f) - m);
        }
        sl[tid] = m + logf(sum);
    }
    __syncthreads();
    if (n < N) {
        float l = sl[nl];
        ((float4*)out)[n * 10 + c1] =
            make_float4(fmaxf(s.x, 0.f) - l, fmaxf(s.y, 0.f) - l,
                        fmaxf(s.z, 0.f) - l, fmaxf(s.w, 0.f) - l);
    }
}

extern "C" void kernel_launch(void* const* d_in, const int* in_sizes, int n_in,
                              void* d_out, int out_size, void* d_ws, size_t ws_size,
                              hipStream_t stream) {
    const float* x  = (const float*)d_in[0];
    const int*   ei = (const int*)d_in[1];
    const float* ew = (const float*)d_in[2];
    const float* W1 = (const float*)d_in[3];
    const float* V1 = (const float*)d_in[4];
    const float* b1 = (const float*)d_in[5];
    const float* W2 = (const float*)d_in[6];
    const float* V2 = (const float*)d_in[7];
    const float* b2 = (const float*)d_in[8];
    float* out = (float*)d_out;

    const int N = in_sizes[0] / F_IN;
    const int E = in_sizes[2];
    const int* src = ei;
    const int* dst = ei + E;

    char* ws = (char*)d_ws;
    size_t off = 0;
    auto carve = [&](size_t bytes) {
        void* p = ws + off;
        off = (off + bytes + 255) & ~size_t(255);
        return p;
    };
    int*      binCursor = (int*)carve(256 * 4);
    int*      rowBeg    = (int*)carve((size_t)N * 4);
    int*      rowEnd    = (int*)carve((size_t)N * 4);
    float*    dinv      = (float*)carve((size_t)N * 4);
    int2*     binned    = (int2*)carve((size_t)256 * BIN_CAP * 8);
    unsigned* csr       = (unsigned*)carve((size_t)256 * BIN_CAP * 4);
    unsigned* xW1p      = (unsigned*)carve((size_t)N * 24 * 4);   // bf16x2 flat
    unsigned* agg1p     = (unsigned*)carve((size_t)N * 24 * 4);   // bf16x2 V1-part
    unsigned* h1p       = (unsigned*)carve((size_t)N * 24 * 4);   // relu'd bf16 h1
    unsigned* xW2p      = (unsigned*)carve((size_t)N * 20 * 4);
    unsigned* agg2p     = (unsigned*)carve((size_t)N * 20 * 4);   // bf16x2 V2-part

    const int B = 256;
    auto cdiv = [](long long a, long long b) { return (int)((a + b - 1) / b); };
    const int nSc = cdiv(E, CHUNK);
    const int nBins = (N + (1 << BIN_SHIFT) - 1) >> BIN_SHIFT;
    const int nGemmBlocks = cdiv(N, 64);

    init_cursor<<<1, 256, 0, stream>>>(binCursor);
    gemm1_binscatter<<<nSc + nGemmBlocks, B, 0, stream>>>(
        x, W1, V1, b1, xW1p, agg1p, N, src, dst, ew, binCursor, binned, E, nSc);
    build_csr<<<nBins, 512, 0, stream>>>(binned, binCursor, rowBeg, rowEnd,
                                         dinv, csr, xW1p, N);

    pull_agg<<<cdiv((long long)N * 12, 384), 384, 0, stream>>>(xW1p, csr, rowBeg,
                                                               rowEnd, agg1p, h1p, N);

    gemm2_kernel<<<nGemmBlocks, B, 0, stream>>>((const short*)h1p, W2, V2, b2,
                                                dinv, xW2p, agg2p, N);

    pull_ls<<<cdiv(N, 32), 320, 0, stream>>>(xW2p, csr, rowBeg, rowEnd,
                                             agg2p, out, N);
}

// Round 8
// 254.873 us; speedup vs baseline: 1.0188x; 1.0121x over previous
//
#include <hip/hip_runtime.h>
#include <math.h>

// ARMA GNN forward: N=100000 nodes, E=1600000 edges, 64 -> 48 -> 40.
// out = log_softmax( relu( A @ (h1@W2) + h1@V2 + b2 ) ), h1 = relu( A @ (x@W1) + x@V1 + b1 )
// A = D^-1/2 (w) D^-1/2.
// R22: pulls are request-throughput-bound, not byte- or ILP-bound (R21's
//      2-deep pipeline was neutral; FETCH is only 1.23x the 8-XCD structural
//      floor). Gathers switched from uint2 (8B/lane, 10/12 reqs per edge-row)
//      to uint4 (16B/lane, 5/6 reqs) — same bytes, HALF the L1/L2 requests.
//      pull_ls: 5 thr/node x 4 u32 cols; pull_agg: 6 thr/node x 4 u32 cols.
//      All 16B-aligned (row strides 80/96B). Pipeline reverted to R16's
//      1-deep csr prefetch. Build chain unchanged (fused gemm1+binscatter,
//      LDS-stash build_csr; binscatter plateaued at ~42us, left as-is).

constexpr int F_IN = 64;
constexpr int HIDDEN = 48;
constexpr int N_CLASS = 40;
constexpr int CHUNK = 4096;       // edges per binscatter block
constexpr int EPT = CHUNK / 256;  // 16 edges/thread, register-staged
constexpr int BIN_SHIFT = 9;      // 512 nodes per bin
constexpr int BIN_CAP = 9216;     // padded bin capacity (mean 8163, sigma ~79)
constexpr int CSR_CAP = 12288;    // LDS stash in build_csr (>= BIN_CAP)

typedef __attribute__((ext_vector_type(8))) short bf16x8;   // 4 VGPRs
typedef __attribute__((ext_vector_type(4))) float f32x4;    // acc frag

// ---- bf16 pack helpers (RNE) ----------------------------------------------
__device__ __forceinline__ short bfr(float f) {
    unsigned u = __float_as_uint(f);
    return (short)((u + 0x7fffu + ((u >> 16) & 1u)) >> 16);
}
__device__ __forceinline__ unsigned pack_bf2(float a, float b) {
    unsigned ua = __float_as_uint(a), ub = __float_as_uint(b);
    ua = (ua + 0x7fffu + ((ua >> 16) & 1u)) >> 16;
    ub = (ub + 0x7fffu + ((ub >> 16) & 1u)) >> 16;
    return ua | (ub << 16);
}
__device__ __forceinline__ float2 unpack_bf2(unsigned u) {
    return make_float2(__uint_as_float(u << 16), __uint_as_float(u & 0xffff0000u));
}
__device__ __forceinline__ bf16x8 cvt8(float4 f0, float4 f1) {
    bf16x8 r;
    r[0] = bfr(f0.x); r[1] = bfr(f0.y); r[2] = bfr(f0.z); r[3] = bfr(f0.w);
    r[4] = bfr(f1.x); r[5] = bfr(f1.y); r[6] = bfr(f1.z); r[7] = bfr(f1.w);
    return r;
}

// ---- init: binCursor[b] = b * BIN_CAP --------------------------------------
__global__ void init_cursor(int* __restrict__ binCursor) {
    binCursor[threadIdx.x] = (int)threadIdx.x * BIN_CAP;
}

// ============================================================================
// FUSED: blocks [0,nSc) = binscatter (register-staged, 1KB LDS hist);
//        blocks [nSc,..) = MFMA layer-1 GEMM (64 nodes/block, 96 cols, K=64).
// ============================================================================
__global__ __launch_bounds__(256) void gemm1_binscatter(
    const float* __restrict__ X, const float* __restrict__ W,
    const float* __restrict__ V, const float* __restrict__ b,
    unsigned* __restrict__ XWp, unsigned* __restrict__ AGGp, int N,
    const int* __restrict__ src, const int* __restrict__ dst,
    const float* __restrict__ w, int* __restrict__ binCursor,
    int2* __restrict__ binned, int E, int nSc) {
    __shared__ char smem[36864];
    int tid = threadIdx.x;

    if ((int)blockIdx.x < nSc) {
        // ---- binscatter path ------------------------------------------------
        int* hist = (int*)smem;   // [256]
        hist[tid] = 0;
        __syncthreads();
        long long e0 = (long long)blockIdx.x * CHUNK;
        int M = (int)min((long long)CHUNK, (long long)E - e0);
        int dv[EPT], sv[EPT], wv[EPT];
#pragma unroll
        for (int q = 0; q < EPT; ++q) {
            int i = tid + q * 256;
            if (i < M) {
                dv[q] = dst[e0 + i];
                sv[q] = src[e0 + i];
                wv[q] = __float_as_int(w[e0 + i]);
                atomicAdd(&hist[dv[q] >> BIN_SHIFT], 1);
            }
        }
        __syncthreads();
        int h = hist[tid];
        int base = h ? atomicAdd(&binCursor[tid], h) : 0;  // global range claim
        __syncthreads();
        hist[tid] = base;  // reuse as cursor
        __syncthreads();
#pragma unroll
        for (int q = 0; q < EPT; ++q) {
            int i = tid + q * 256;
            if (i < M) {
                int d = dv[q];
                int p = atomicAdd(&hist[d >> BIN_SHIFT], 1);  // LDS cursor
                binned[p] = make_int2(((d & 511) << 17) | sv[q], wv[q]);
            }
        }
        return;
    }

    // ---- gemm1 path ---------------------------------------------------------
    short* sWT = (short*)smem;                 // [96][64]
    float* ep = (float*)(smem + 12288);        // [64][96]
    for (int i = tid; i < 96 * 64; i += 256) {
        int c = i >> 6, k = i & 63;
        float v = (c < 48) ? W[k * 48 + c] : V[k * 48 + (c - 48)];
        sWT[i] = bfr(v);
    }
    __syncthreads();

    int lane = tid & 63, wvq = tid >> 6;
    int m = lane & 15, quad = lane >> 4;
    int nb0 = ((int)blockIdx.x - nSc) * 64;
    int n = nb0 + wvq * 16 + m;

    bf16x8 a0, a1;
    if (n < N) {
        const float4* xr = (const float4*)(X + (size_t)n * 64 + quad * 8);
        a0 = cvt8(xr[0], xr[1]);
        const float4* xr2 = (const float4*)(X + (size_t)n * 64 + 32 + quad * 8);
        a1 = cvt8(xr2[0], xr2[1]);
    } else {
        for (int j = 0; j < 8; ++j) { a0[j] = 0; a1[j] = 0; }
    }

    f32x4 acc[6];
#pragma unroll
    for (int ct = 0; ct < 6; ++ct) acc[ct] = (f32x4){0.f, 0.f, 0.f, 0.f};
#pragma unroll
    for (int ct = 0; ct < 6; ++ct) {
        bf16x8 b0 = *(const bf16x8*)(sWT + (ct * 16 + m) * 64 + quad * 8);
        bf16x8 b1 = *(const bf16x8*)(sWT + (ct * 16 + m) * 64 + 32 + quad * 8);
        acc[ct] = __builtin_amdgcn_mfma_f32_16x16x32_bf16(a0, b0, acc[ct], 0, 0, 0);
        acc[ct] = __builtin_amdgcn_mfma_f32_16x16x32_bf16(a1, b1, acc[ct], 0, 0, 0);
    }
#pragma unroll
    for (int ct = 0; ct < 6; ++ct)
#pragma unroll
        for (int r = 0; r < 4; ++r)
            ep[(wvq * 16 + quad * 4 + r) * 96 + ct * 16 + m] = acc[ct][r];
    __syncthreads();
    for (int i = tid; i < 64 * 24; i += 256) {
        int r = i / 24, c2 = i - r * 24;
        int node = nb0 + r;
        if (node >= N) continue;
        float w0 = ep[r * 96 + 2 * c2], w1 = ep[r * 96 + 2 * c2 + 1];
        XWp[node * 24 + c2] = pack_bf2(w0, w1);
        float v0 = ep[r * 96 + 48 + 2 * c2], v1 = ep[r * 96 + 48 + 2 * c2 + 1];
        float2 bb = ((const float2*)b)[c2];
        AGGp[node * 24 + c2] = pack_bf2(v0 + bb.x, v1 + bb.y);
    }
}

// ---- build_csr: per-bin LDS counting sort -> compressed 4B CSR -------------
__global__ __launch_bounds__(512) void build_csr(const int2* __restrict__ binned,
                                                 const int* __restrict__ binCursor,
                                                 int* __restrict__ rowBeg,
                                                 int* __restrict__ rowEnd,
                                                 float* __restrict__ dinv,
                                                 unsigned* __restrict__ csr,
                                                 unsigned* __restrict__ XW1p, int N) {
    __shared__ int sx[CSR_CAP];
    __shared__ int sw[CSR_CAP];
    __shared__ int cntL[512];
    __shared__ float degL[512];  // deg sums, then dinv values
    __shared__ int scanL[512];
    int b = blockIdx.x, tid = threadIdx.x;
    int e0 = b * BIN_CAP;
    int M = min(binCursor[b] - e0, BIN_CAP);  // clamp (never hit)
    cntL[tid] = 0;
    degL[tid] = 0.f;
    __syncthreads();
    for (int i = tid; i < M; i += 512) {
        int2 p = binned[e0 + i];
        sx[i] = p.x;
        sw[i] = p.y;
        int dl = ((unsigned)p.x) >> 17;
        atomicAdd(&cntL[dl], 1);
        atomicAdd(&degL[dl], __int_as_float(p.y));
    }
    __syncthreads();
    int v = cntL[tid];
    scanL[tid] = v;
    __syncthreads();
#pragma unroll
    for (int o = 1; o < 512; o <<= 1) {
        int u = (tid >= o) ? scanL[tid - o] : 0;
        __syncthreads();
        scanL[tid] += u;
        __syncthreads();
    }
    int excl = scanL[tid] - v;
    int node = (b << BIN_SHIFT) + tid;
    float dg = degL[tid];
    float dv = dg > 0.f ? rsqrtf(dg) : 0.f;
    if (node < N) {
        rowBeg[node] = e0 + excl;
        rowEnd[node] = e0 + excl + v;
        dinv[node] = dv;
    }
    cntL[tid] = e0 + excl;  // reuse as global write cursor
    degL[tid] = dv;         // reuse as dinv table
    __syncthreads();
    for (int i = tid; i < M; i += 512) {
        int px = sx[i], pw = sw[i];
        int dl = ((unsigned)px) >> 17;
        int pos = atomicAdd(&cntL[dl], 1);  // LDS atomic
        float wn = __int_as_float(pw) * degL[dl];  // fold dinv[dst] in now
        unsigned uw = __float_as_uint(wn);
        uw = (uw + 0x7fffu + ((uw >> 16) & 1u)) >> 16;  // bf16 RNE; positive -> <=0x7FFF
        csr[pos] = ((unsigned)(px & 0x1FFFF) << 15) | uw;
    }
    // ---- fold of scale_xw: scale this bin's xW1p rows by dinv (coalesced) ----
    int nb0 = b << BIN_SHIFT;
    for (int i = tid; i < 512 * 24; i += 512) {
        int nl = i / 24, c = i - nl * 24;
        int nn = nb0 + nl;
        if (nn >= N) break;
        float dvn = degL[nl];
        float2 u = unpack_bf2(XW1p[nn * 24 + c]);
        XW1p[nn * 24 + c] = pack_bf2(u.x * dvn, u.y * dvn);
    }
}

// ---- single-edge accumulate (uint4 gather: 4 u32 cols = 8 bf16) ------------
template <int W>
__device__ __forceinline__ void edge1w(const unsigned* __restrict__ XWp,
                                       unsigned p, int c, float4& s0, float4& s1) {
    uint4 u = *(const uint4*)(XWp + (p >> 15) * W + c);
    float nr = __uint_as_float((p & 0x7FFFu) << 16);
    float2 x0 = unpack_bf2(u.x), x1 = unpack_bf2(u.y);
    float2 x2 = unpack_bf2(u.z), x3 = unpack_bf2(u.w);
    s0.x = fmaf(x0.x, nr, s0.x); s0.y = fmaf(x0.y, nr, s0.y);
    s0.z = fmaf(x1.x, nr, s0.z); s0.w = fmaf(x1.y, nr, s0.w);
    s1.x = fmaf(x2.x, nr, s1.x); s1.y = fmaf(x2.y, nr, s1.y);
    s1.z = fmaf(x3.x, nr, s1.z); s1.w = fmaf(x3.y, nr, s1.w);
}

// ---- 4-edge gather+fma body (csr word in register; uint4 gathers) ----------
template <int W>
__device__ __forceinline__ void edge4w(const unsigned* __restrict__ XWp, uint4 p4,
                                       int c, float4& s0, float4& s1) {
    uint4 u0 = *(const uint4*)(XWp + (p4.x >> 15) * W + c);
    uint4 u1 = *(const uint4*)(XWp + (p4.y >> 15) * W + c);
    uint4 u2 = *(const uint4*)(XWp + (p4.z >> 15) * W + c);
    uint4 u3 = *(const uint4*)(XWp + (p4.w >> 15) * W + c);
    float n0 = __uint_as_float((p4.x & 0x7FFFu) << 16);
    float n1 = __uint_as_float((p4.y & 0x7FFFu) << 16);
    float n2 = __uint_as_float((p4.z & 0x7FFFu) << 16);
    float n3 = __uint_as_float((p4.w & 0x7FFFu) << 16);
    {
        float2 a0 = unpack_bf2(u0.x), a1 = unpack_bf2(u0.y);
        float2 a2 = unpack_bf2(u0.z), a3 = unpack_bf2(u0.w);
        s0.x = fmaf(a0.x, n0, s0.x); s0.y = fmaf(a0.y, n0, s0.y);
        s0.z = fmaf(a1.x, n0, s0.z); s0.w = fmaf(a1.y, n0, s0.w);
        s1.x = fmaf(a2.x, n0, s1.x); s1.y = fmaf(a2.y, n0, s1.y);
        s1.z = fmaf(a3.x, n0, s1.z); s1.w = fmaf(a3.y, n0, s1.w);
    }
    {
        float2 a0 = unpack_bf2(u1.x), a1 = unpack_bf2(u1.y);
        float2 a2 = unpack_bf2(u1.z), a3 = unpack_bf2(u1.w);
        s0.x = fmaf(a0.x, n1, s0.x); s0.y = fmaf(a0.y, n1, s0.y);
        s0.z = fmaf(a1.x, n1, s0.z); s0.w = fmaf(a1.y, n1, s0.w);
        s1.x = fmaf(a2.x, n1, s1.x); s1.y = fmaf(a2.y, n1, s1.y);
        s1.z = fmaf(a3.x, n1, s1.z); s1.w = fmaf(a3.y, n1, s1.w);
    }
    {
        float2 a0 = unpack_bf2(u2.x), a1 = unpack_bf2(u2.y);
        float2 a2 = unpack_bf2(u2.z), a3 = unpack_bf2(u2.w);
        s0.x = fmaf(a0.x, n2, s0.x); s0.y = fmaf(a0.y, n2, s0.y);
        s0.z = fmaf(a1.x, n2, s0.z); s0.w = fmaf(a1.y, n2, s0.w);
        s1.x = fmaf(a2.x, n2, s1.x); s1.y = fmaf(a2.y, n2, s1.y);
        s1.z = fmaf(a3.x, n2, s1.z); s1.w = fmaf(a3.y, n2, s1.w);
    }
    {
        float2 a0 = unpack_bf2(u3.x), a1 = unpack_bf2(u3.y);
        float2 a2 = unpack_bf2(u3.z), a3 = unpack_bf2(u3.w);
        s0.x = fmaf(a0.x, n3, s0.x); s0.y = fmaf(a0.y, n3, s0.y);
        s0.z = fmaf(a1.x, n3, s0.z); s0.w = fmaf(a1.y, n3, s0.w);
        s1.x = fmaf(a2.x, n3, s1.x); s1.y = fmaf(a2.y, n3, s1.y);
        s1.z = fmaf(a3.x, n3, s1.z); s1.w = fmaf(a3.y, n3, s1.w);
    }
}

// ---- row accumulate: 4 u32 cols/thread, uint4 gathers, aligned uint4 csr
//      loads, 1-deep csr prefetch (R16 structure).
template <int W>
__device__ __forceinline__ void row_accum4(const unsigned* __restrict__ XWp,
                                           const unsigned* __restrict__ csr,
                                           int j, int end, int c,
                                           float4& s0, float4& s1) {
    // head: scalar until j is 4-aligned (bin bases are 4-edge aligned)
    while (j < end && (j & 3)) {
        edge1w<W>(XWp, csr[j++], c, s0, s1);
    }
    int nch = (end - j) >> 2;
    if (nch > 0) {
        uint4 p4 = *(const uint4*)(csr + j);
        for (int k = 1; k < nch; ++k) {
            uint4 p4n = *(const uint4*)(csr + j + (k << 2));  // prefetch next chunk
            edge4w<W>(XWp, p4, c, s0, s1);
            p4 = p4n;
        }
        edge4w<W>(XWp, p4, c, s0, s1);
        j += nch << 2;
    }
    for (; j < end; ++j) {
        edge1w<W>(XWp, csr[j], c, s0, s1);
    }
}

// ---- layer-1 pull: h1[n] = relu(bf16(AGG1p[n]) + sum_j xWp[src_j]*nrm_j) ---
// 6 threads/node, 4 u32 cols each (uint4 gathers); block 384 = 64 nodes.
__global__ __launch_bounds__(384) void pull_agg(const unsigned* __restrict__ XWp,
                                                const unsigned* __restrict__ csr,
                                                const int* __restrict__ rowBeg,
                                                const int* __restrict__ rowEnd,
                                                const unsigned* __restrict__ AGG1p,
                                                unsigned* __restrict__ H1p, int N) {
    int t = blockIdx.x * blockDim.x + threadIdx.x;
    int n = t / 6, c1 = t - n * 6;
    if (n >= N) return;
    int c = 4 * c1;
    uint4 a = *(const uint4*)(AGG1p + n * 24 + c);
    float2 f0 = unpack_bf2(a.x), f1 = unpack_bf2(a.y);
    float2 f2 = unpack_bf2(a.z), f3 = unpack_bf2(a.w);
    float4 s0 = make_float4(f0.x, f0.y, f1.x, f1.y);
    float4 s1 = make_float4(f2.x, f2.y, f3.x, f3.y);
    row_accum4<24>(XWp, csr, rowBeg[n], rowEnd[n], c, s0, s1);
    uint4 o;
    o.x = pack_bf2(fmaxf(s0.x, 0.f), fmaxf(s0.y, 0.f));
    o.y = pack_bf2(fmaxf(s0.z, 0.f), fmaxf(s0.w, 0.f));
    o.z = pack_bf2(fmaxf(s1.x, 0.f), fmaxf(s1.y, 0.f));
    o.w = pack_bf2(fmaxf(s1.z, 0.f), fmaxf(s1.w, 0.f));
    *(uint4*)(H1p + n * 24 + c) = o;  // relu'd bf16 h1
}

// ============================================================================
// MFMA layer-2 GEMM: 64 nodes/block, 80 cols (W2|V2), K=48 zero-padded to 64.
// ============================================================================
__global__ __launch_bounds__(256) void gemm2_kernel(
    const short* __restrict__ H1, const float* __restrict__ W,
    const float* __restrict__ V, const float* __restrict__ b,
    const float* __restrict__ dinv, unsigned* __restrict__ XWp,
    unsigned* __restrict__ AGGp, int N) {
    __shared__ char smem[30720];
    short* sWT = (short*)smem;            // [80][64], k>=48 zero
    float* ep = (float*)(smem + 10240);   // [64][80]
    int tid = threadIdx.x;
    for (int i = tid; i < 80 * 64; i += 256) {
        int c = i >> 6, k = i & 63;
        float v = 0.f;
        if (k < 48) v = (c < 40) ? W[k * 40 + c] : V[k * 40 + (c - 40)];
        sWT[i] = bfr(v);
    }
    __syncthreads();

    int lane = tid & 63, wv = tid >> 6;
    int m = lane & 15, quad = lane >> 4;
    int nb0 = (int)blockIdx.x * 64;
    int n = nb0 + wv * 16 + m;

    bf16x8 a0, a1;
    if (n < N) {
        a0 = *(const bf16x8*)(H1 + (size_t)n * 48 + quad * 8);
        if (quad < 2) {
            a1 = *(const bf16x8*)(H1 + (size_t)n * 48 + 32 + quad * 8);
        } else {
            for (int j = 0; j < 8; ++j) a1[j] = 0;
        }
    } else {
        for (int j = 0; j < 8; ++j) { a0[j] = 0; a1[j] = 0; }
    }

    f32x4 acc[5];
#pragma unroll
    for (int ct = 0; ct < 5; ++ct) acc[ct] = (f32x4){0.f, 0.f, 0.f, 0.f};
#pragma unroll
    for (int ct = 0; ct < 5; ++ct) {
        bf16x8 b0 = *(const bf16x8*)(sWT + (ct * 16 + m) * 64 + quad * 8);
        bf16x8 b1 = *(const bf16x8*)(sWT + (ct * 16 + m) * 64 + 32 + quad * 8);
        acc[ct] = __builtin_amdgcn_mfma_f32_16x16x32_bf16(a0, b0, acc[ct], 0, 0, 0);
        acc[ct] = __builtin_amdgcn_mfma_f32_16x16x32_bf16(a1, b1, acc[ct], 0, 0, 0);
    }
#pragma unroll
    for (int ct = 0; ct < 5; ++ct)
#pragma unroll
        for (int r = 0; r < 4; ++r)
            ep[(wv * 16 + quad * 4 + r) * 80 + ct * 16 + m] = acc[ct][r];
    __syncthreads();
    for (int i = tid; i < 64 * 20; i += 256) {
        int r = i / 20, c2 = i - r * 20;
        int node = nb0 + r;
        if (node >= N) continue;
        float dv = dinv[node];
        float w0 = ep[r * 80 + 2 * c2], w1 = ep[r * 80 + 2 * c2 + 1];
        XWp[node * 20 + c2] = pack_bf2(w0 * dv, w1 * dv);
        float v0 = ep[r * 80 + 40 + 2 * c2], v1 = ep[r * 80 + 40 + 2 * c2 + 1];
        float2 bb = ((const float2*)b)[c2];
        AGGp[node * 20 + c2] = pack_bf2(v0 + bb.x, v1 + bb.y);
    }
}

// ---- layer-2 pull fused with log_softmax(relu(.)) --------------------------
// 5 threads/node, 4 u32 cols each (uint4 gathers); block 320 = 64 nodes.
__global__ __launch_bounds__(320) void pull_ls(const unsigned* __restrict__ XWp,
                                               const unsigned* __restrict__ csr,
                                               const int* __restrict__ rowBeg,
                                               const int* __restrict__ rowEnd,
                                               const unsigned* __restrict__ AGG2p,
                                               float* __restrict__ out, int N) {
    __shared__ float4 sbuf[64 * 10];
    __shared__ float sl[64];
    int tid = threadIdx.x;
    int nl = tid / 5, c1 = tid - nl * 5;
    int n = blockIdx.x * 64 + nl;
    int c = 4 * c1;
    float4 s0 = make_float4(0.f, 0.f, 0.f, 0.f);
    float4 s1 = make_float4(0.f, 0.f, 0.f, 0.f);
    if (n < N) {
        uint4 a = *(const uint4*)(AGG2p + n * 20 + c);
        float2 f0 = unpack_bf2(a.x), f1 = unpack_bf2(a.y);
        float2 f2 = unpack_bf2(a.z), f3 = unpack_bf2(a.w);
        s0 = make_float4(f0.x, f0.y, f1.x, f1.y);
        s1 = make_float4(f2.x, f2.y, f3.x, f3.y);
        row_accum4<20>(XWp, csr, rowBeg[n], rowEnd[n], c, s0, s1);
    }
    sbuf[(nl * 5 + c1) * 2] = s0;
    sbuf[(nl * 5 + c1) * 2 + 1] = s1;
    __syncthreads();
    if (tid < 64) {
        float m = 0.f;  // relu floor
        for (int k = 0; k < 10; ++k) {
            float4 v = sbuf[tid * 10 + k];
            m = fmaxf(m, fmaxf(fmaxf(v.x, v.y), fmaxf(v.z, v.w)));
        }
        float sum = 0.f;
        for (int k = 0; k < 10; ++k) {
            float4 v = sbuf[tid * 10 + k];
            sum += expf(fmaxf(v.x, 0.f) - m) + expf(fmaxf(v.y, 0.f) - m) +
                   expf(fmaxf(v.z, 0.f) - m) + expf(fmaxf(v.w, 0.f) - m);
        }
        sl[tid] = m + logf(sum);
    }
    __syncthreads();
    if (n < N) {
        float l = sl[nl];
        float4* op = (float4*)(out + (size_t)n * 40 + 8 * c1);
        op[0] = make_float4(fmaxf(s0.x, 0.f) - l, fmaxf(s0.y, 0.f) - l,
                            fmaxf(s0.z, 0.f) - l, fmaxf(s0.w, 0.f) - l);
        op[1] = make_float4(fmaxf(s1.x, 0.f) - l, fmaxf(s1.y, 0.f) - l,
                            fmaxf(s1.z, 0.f) - l, fmaxf(s1.w, 0.f) - l);
    }
}

extern "C" void kernel_launch(void* const* d_in, const int* in_sizes, int n_in,
                              void* d_out, int out_size, void* d_ws, size_t ws_size,
                              hipStream_t stream) {
    const float* x  = (const float*)d_in[0];
    const int*   ei = (const int*)d_in[1];
    const float* ew = (const float*)d_in[2];
    const float* W1 = (const float*)d_in[3];
    const float* V1 = (const float*)d_in[4];
    const float* b1 = (const float*)d_in[5];
    const float* W2 = (const float*)d_in[6];
    const float* V2 = (const float*)d_in[7];
    const float* b2 = (const float*)d_in[8];
    float* out = (float*)d_out;

    const int N = in_sizes[0] / F_IN;
    const int E = in_sizes[2];
    const int* src = ei;
    const int* dst = ei + E;

    char* ws = (char*)d_ws;
    size_t off = 0;
    auto carve = [&](size_t bytes) {
        void* p = ws + off;
        off = (off + bytes + 255) & ~size_t(255);
        return p;
    };
    int*      binCursor = (int*)carve(256 * 4);
    int*      rowBeg    = (int*)carve((size_t)N * 4);
    int*      rowEnd    = (int*)carve((size_t)N * 4);
    float*    dinv      = (float*)carve((size_t)N * 4);
    int2*     binned    = (int2*)carve((size_t)256 * BIN_CAP * 8);
    unsigned* csr       = (unsigned*)carve((size_t)256 * BIN_CAP * 4);
    unsigned* xW1p      = (unsigned*)carve((size_t)N * 24 * 4);   // bf16x2 flat
    unsigned* agg1p     = (unsigned*)carve((size_t)N * 24 * 4);   // bf16x2 V1-part
    unsigned* h1p       = (unsigned*)carve((size_t)N * 24 * 4);   // relu'd bf16 h1
    unsigned* xW2p      = (unsigned*)carve((size_t)N * 20 * 4);
    unsigned* agg2p     = (unsigned*)carve((size_t)N * 20 * 4);   // bf16x2 V2-part

    const int B = 256;
    auto cdiv = [](long long a, long long b) { return (int)((a + b - 1) / b); };
    const int nSc = cdiv(E, CHUNK);
    const int nBins = (N + (1 << BIN_SHIFT) - 1) >> BIN_SHIFT;
    const int nGemmBlocks = cdiv(N, 64);

    init_cursor<<<1, 256, 0, stream>>>(binCursor);
    gemm1_binscatter<<<nSc + nGemmBlocks, B, 0, stream>>>(
        x, W1, V1, b1, xW1p, agg1p, N, src, dst, ew, binCursor, binned, E, nSc);
    build_csr<<<nBins, 512, 0, stream>>>(binned, binCursor, rowBeg, rowEnd,
                                         dinv, csr, xW1p, N);

    pull_agg<<<cdiv((long long)N * 6, 384), 384, 0, stream>>>(xW1p, csr, rowBeg,
                                                              rowEnd, agg1p, h1p, N);

    gemm2_kernel<<<nGemmBlocks, B, 0, stream>>>((const short*)h1p, W2, V2, b2,
                                                dinv, xW2p, agg2p, N);

    pull_ls<<<cdiv(N, 64), 320, 0, stream>>>(xW2p, csr, rowBeg, rowEnd,
                                             agg2p, out, N);
}

// Round 9
// 253.064 us; speedup vs baseline: 1.0260x; 1.0072x over previous
//
#include <hip/hip_runtime.h>
#include <math.h>

// ARMA GNN forward: N=100000 nodes, E=1600000 edges, 64 -> 48 -> 40.
// out = log_softmax( relu( A @ (h1@W2) + h1@V2 + b2 ) ), h1 = relu( A @ (x@W1) + x@V1 + b1 )
// A = D^-1/2 (w) D^-1/2.
// R23: pull_agg + gemm2 FUSED (gemm2 is row-local: xW2p[n]/agg2p[n] depend
//      only on h1[n]). Block = 64 nodes: phase 1 pulls h1 rows into LDS
//      (6 thr/node, uint4 gathers, unchanged), barrier, phase 2 = gemm2 MFMA
//      body reading A-frags from LDS. Deletes h1p round-trip (19 MB), the
//      gemm2 dispatch (~12us serial), and one launch gap; MFMA hides under
//      pull latency slack. LDS 36.9KB -> 4 blocks/CU @ 384 thr. Rest
//      identical to R22 (uint4 gathers, fused gemm1+binscatter, build_csr).

constexpr int F_IN = 64;
constexpr int HIDDEN = 48;
constexpr int N_CLASS = 40;
constexpr int CHUNK = 4096;       // edges per binscatter block
constexpr int EPT = CHUNK / 256;  // 16 edges/thread, register-staged
constexpr int BIN_SHIFT = 9;      // 512 nodes per bin
constexpr int BIN_CAP = 9216;     // padded bin capacity (mean 8163, sigma ~79)
constexpr int CSR_CAP = 12288;    // LDS stash in build_csr (>= BIN_CAP)

typedef __attribute__((ext_vector_type(8))) short bf16x8;   // 4 VGPRs
typedef __attribute__((ext_vector_type(4))) float f32x4;    // acc frag

// ---- bf16 pack helpers (RNE) ----------------------------------------------
__device__ __forceinline__ short bfr(float f) {
    unsigned u = __float_as_uint(f);
    return (short)((u + 0x7fffu + ((u >> 16) & 1u)) >> 16);
}
__device__ __forceinline__ unsigned pack_bf2(float a, float b) {
    unsigned ua = __float_as_uint(a), ub = __float_as_uint(b);
    ua = (ua + 0x7fffu + ((ua >> 16) & 1u)) >> 16;
    ub = (ub + 0x7fffu + ((ub >> 16) & 1u)) >> 16;
    return ua | (ub << 16);
}
__device__ __forceinline__ float2 unpack_bf2(unsigned u) {
    return make_float2(__uint_as_float(u << 16), __uint_as_float(u & 0xffff0000u));
}
__device__ __forceinline__ bf16x8 cvt8(float4 f0, float4 f1) {
    bf16x8 r;
    r[0] = bfr(f0.x); r[1] = bfr(f0.y); r[2] = bfr(f0.z); r[3] = bfr(f0.w);
    r[4] = bfr(f1.x); r[5] = bfr(f1.y); r[6] = bfr(f1.z); r[7] = bfr(f1.w);
    return r;
}

// ---- init: binCursor[b] = b * BIN_CAP --------------------------------------
__global__ void init_cursor(int* __restrict__ binCursor) {
    binCursor[threadIdx.x] = (int)threadIdx.x * BIN_CAP;
}

// ============================================================================
// FUSED: blocks [0,nSc) = binscatter (register-staged, 1KB LDS hist);
//        blocks [nSc,..) = MFMA layer-1 GEMM (64 nodes/block, 96 cols, K=64).
// ============================================================================
__global__ __launch_bounds__(256) void gemm1_binscatter(
    const float* __restrict__ X, const float* __restrict__ W,
    const float* __restrict__ V, const float* __restrict__ b,
    unsigned* __restrict__ XWp, unsigned* __restrict__ AGGp, int N,
    const int* __restrict__ src, const int* __restrict__ dst,
    const float* __restrict__ w, int* __restrict__ binCursor,
    int2* __restrict__ binned, int E, int nSc) {
    __shared__ char smem[36864];
    int tid = threadIdx.x;

    if ((int)blockIdx.x < nSc) {
        // ---- binscatter path ------------------------------------------------
        int* hist = (int*)smem;   // [256]
        hist[tid] = 0;
        __syncthreads();
        long long e0 = (long long)blockIdx.x * CHUNK;
        int M = (int)min((long long)CHUNK, (long long)E - e0);
        int dv[EPT], sv[EPT], wv[EPT];
#pragma unroll
        for (int q = 0; q < EPT; ++q) {
            int i = tid + q * 256;
            if (i < M) {
                dv[q] = dst[e0 + i];
                sv[q] = src[e0 + i];
                wv[q] = __float_as_int(w[e0 + i]);
                atomicAdd(&hist[dv[q] >> BIN_SHIFT], 1);
            }
        }
        __syncthreads();
        int h = hist[tid];
        int base = h ? atomicAdd(&binCursor[tid], h) : 0;  // global range claim
        __syncthreads();
        hist[tid] = base;  // reuse as cursor
        __syncthreads();
#pragma unroll
        for (int q = 0; q < EPT; ++q) {
            int i = tid + q * 256;
            if (i < M) {
                int d = dv[q];
                int p = atomicAdd(&hist[d >> BIN_SHIFT], 1);  // LDS cursor
                binned[p] = make_int2(((d & 511) << 17) | sv[q], wv[q]);
            }
        }
        return;
    }

    // ---- gemm1 path ---------------------------------------------------------
    short* sWT = (short*)smem;                 // [96][64]
    float* ep = (float*)(smem + 12288);        // [64][96]
    for (int i = tid; i < 96 * 64; i += 256) {
        int c = i >> 6, k = i & 63;
        float v = (c < 48) ? W[k * 48 + c] : V[k * 48 + (c - 48)];
        sWT[i] = bfr(v);
    }
    __syncthreads();

    int lane = tid & 63, wvq = tid >> 6;
    int m = lane & 15, quad = lane >> 4;
    int nb0 = ((int)blockIdx.x - nSc) * 64;
    int n = nb0 + wvq * 16 + m;

    bf16x8 a0, a1;
    if (n < N) {
        const float4* xr = (const float4*)(X + (size_t)n * 64 + quad * 8);
        a0 = cvt8(xr[0], xr[1]);
        const float4* xr2 = (const float4*)(X + (size_t)n * 64 + 32 + quad * 8);
        a1 = cvt8(xr2[0], xr2[1]);
    } else {
        for (int j = 0; j < 8; ++j) { a0[j] = 0; a1[j] = 0; }
    }

    f32x4 acc[6];
#pragma unroll
    for (int ct = 0; ct < 6; ++ct) acc[ct] = (f32x4){0.f, 0.f, 0.f, 0.f};
#pragma unroll
    for (int ct = 0; ct < 6; ++ct) {
        bf16x8 b0 = *(const bf16x8*)(sWT + (ct * 16 + m) * 64 + quad * 8);
        bf16x8 b1 = *(const bf16x8*)(sWT + (ct * 16 + m) * 64 + 32 + quad * 8);
        acc[ct] = __builtin_amdgcn_mfma_f32_16x16x32_bf16(a0, b0, acc[ct], 0, 0, 0);
        acc[ct] = __builtin_amdgcn_mfma_f32_16x16x32_bf16(a1, b1, acc[ct], 0, 0, 0);
    }
#pragma unroll
    for (int ct = 0; ct < 6; ++ct)
#pragma unroll
        for (int r = 0; r < 4; ++r)
            ep[(wvq * 16 + quad * 4 + r) * 96 + ct * 16 + m] = acc[ct][r];
    __syncthreads();
    for (int i = tid; i < 64 * 24; i += 256) {
        int r = i / 24, c2 = i - r * 24;
        int node = nb0 + r;
        if (node >= N) continue;
        float w0 = ep[r * 96 + 2 * c2], w1 = ep[r * 96 + 2 * c2 + 1];
        XWp[node * 24 + c2] = pack_bf2(w0, w1);
        float v0 = ep[r * 96 + 48 + 2 * c2], v1 = ep[r * 96 + 48 + 2 * c2 + 1];
        float2 bb = ((const float2*)b)[c2];
        AGGp[node * 24 + c2] = pack_bf2(v0 + bb.x, v1 + bb.y);
    }
}

// ---- build_csr: per-bin LDS counting sort -> compressed 4B CSR -------------
__global__ __launch_bounds__(512) void build_csr(const int2* __restrict__ binned,
                                                 const int* __restrict__ binCursor,
                                                 int* __restrict__ rowBeg,
                                                 int* __restrict__ rowEnd,
                                                 float* __restrict__ dinv,
                                                 unsigned* __restrict__ csr,
                                                 unsigned* __restrict__ XW1p, int N) {
    __shared__ int sx[CSR_CAP];
    __shared__ int sw[CSR_CAP];
    __shared__ int cntL[512];
    __shared__ float degL[512];  // deg sums, then dinv values
    __shared__ int scanL[512];
    int b = blockIdx.x, tid = threadIdx.x;
    int e0 = b * BIN_CAP;
    int M = min(binCursor[b] - e0, BIN_CAP);  // clamp (never hit)
    cntL[tid] = 0;
    degL[tid] = 0.f;
    __syncthreads();
    for (int i = tid; i < M; i += 512) {
        int2 p = binned[e0 + i];
        sx[i] = p.x;
        sw[i] = p.y;
        int dl = ((unsigned)p.x) >> 17;
        atomicAdd(&cntL[dl], 1);
        atomicAdd(&degL[dl], __int_as_float(p.y));
    }
    __syncthreads();
    int v = cntL[tid];
    scanL[tid] = v;
    __syncthreads();
#pragma unroll
    for (int o = 1; o < 512; o <<= 1) {
        int u = (tid >= o) ? scanL[tid - o] : 0;
        __syncthreads();
        scanL[tid] += u;
        __syncthreads();
    }
    int excl = scanL[tid] - v;
    int node = (b << BIN_SHIFT) + tid;
    float dg = degL[tid];
    float dv = dg > 0.f ? rsqrtf(dg) : 0.f;
    if (node < N) {
        rowBeg[node] = e0 + excl;
        rowEnd[node] = e0 + excl + v;
        dinv[node] = dv;
    }
    cntL[tid] = e0 + excl;  // reuse as global write cursor
    degL[tid] = dv;         // reuse as dinv table
    __syncthreads();
    for (int i = tid; i < M; i += 512) {
        int px = sx[i], pw = sw[i];
        int dl = ((unsigned)px) >> 17;
        int pos = atomicAdd(&cntL[dl], 1);  // LDS atomic
        float wn = __int_as_float(pw) * degL[dl];  // fold dinv[dst] in now
        unsigned uw = __float_as_uint(wn);
        uw = (uw + 0x7fffu + ((uw >> 16) & 1u)) >> 16;  // bf16 RNE; positive -> <=0x7FFF
        csr[pos] = ((unsigned)(px & 0x1FFFF) << 15) | uw;
    }
    // ---- fold of scale_xw: scale this bin's xW1p rows by dinv (coalesced) ----
    int nb0 = b << BIN_SHIFT;
    for (int i = tid; i < 512 * 24; i += 512) {
        int nl = i / 24, c = i - nl * 24;
        int nn = nb0 + nl;
        if (nn >= N) break;
        float dvn = degL[nl];
        float2 u = unpack_bf2(XW1p[nn * 24 + c]);
        XW1p[nn * 24 + c] = pack_bf2(u.x * dvn, u.y * dvn);
    }
}

// ---- single-edge accumulate (uint4 gather: 4 u32 cols = 8 bf16) ------------
template <int W>
__device__ __forceinline__ void edge1w(const unsigned* __restrict__ XWp,
                                       unsigned p, int c, float4& s0, float4& s1) {
    uint4 u = *(const uint4*)(XWp + (p >> 15) * W + c);
    float nr = __uint_as_float((p & 0x7FFFu) << 16);
    float2 x0 = unpack_bf2(u.x), x1 = unpack_bf2(u.y);
    float2 x2 = unpack_bf2(u.z), x3 = unpack_bf2(u.w);
    s0.x = fmaf(x0.x, nr, s0.x); s0.y = fmaf(x0.y, nr, s0.y);
    s0.z = fmaf(x1.x, nr, s0.z); s0.w = fmaf(x1.y, nr, s0.w);
    s1.x = fmaf(x2.x, nr, s1.x); s1.y = fmaf(x2.y, nr, s1.y);
    s1.z = fmaf(x3.x, nr, s1.z); s1.w = fmaf(x3.y, nr, s1.w);
}

// ---- 4-edge gather+fma body (csr word in register; uint4 gathers) ----------
template <int W>
__device__ __forceinline__ void edge4w(const unsigned* __restrict__ XWp, uint4 p4,
                                       int c, float4& s0, float4& s1) {
    uint4 u0 = *(const uint4*)(XWp + (p4.x >> 15) * W + c);
    uint4 u1 = *(const uint4*)(XWp + (p4.y >> 15) * W + c);
    uint4 u2 = *(const uint4*)(XWp + (p4.z >> 15) * W + c);
    uint4 u3 = *(const uint4*)(XWp + (p4.w >> 15) * W + c);
    float n0 = __uint_as_float((p4.x & 0x7FFFu) << 16);
    float n1 = __uint_as_float((p4.y & 0x7FFFu) << 16);
    float n2 = __uint_as_float((p4.z & 0x7FFFu) << 16);
    float n3 = __uint_as_float((p4.w & 0x7FFFu) << 16);
    {
        float2 a0 = unpack_bf2(u0.x), a1 = unpack_bf2(u0.y);
        float2 a2 = unpack_bf2(u0.z), a3 = unpack_bf2(u0.w);
        s0.x = fmaf(a0.x, n0, s0.x); s0.y = fmaf(a0.y, n0, s0.y);
        s0.z = fmaf(a1.x, n0, s0.z); s0.w = fmaf(a1.y, n0, s0.w);
        s1.x = fmaf(a2.x, n0, s1.x); s1.y = fmaf(a2.y, n0, s1.y);
        s1.z = fmaf(a3.x, n0, s1.z); s1.w = fmaf(a3.y, n0, s1.w);
    }
    {
        float2 a0 = unpack_bf2(u1.x), a1 = unpack_bf2(u1.y);
        float2 a2 = unpack_bf2(u1.z), a3 = unpack_bf2(u1.w);
        s0.x = fmaf(a0.x, n1, s0.x); s0.y = fmaf(a0.y, n1, s0.y);
        s0.z = fmaf(a1.x, n1, s0.z); s0.w = fmaf(a1.y, n1, s0.w);
        s1.x = fmaf(a2.x, n1, s1.x); s1.y = fmaf(a2.y, n1, s1.y);
        s1.z = fmaf(a3.x, n1, s1.z); s1.w = fmaf(a3.y, n1, s1.w);
    }
    {
        float2 a0 = unpack_bf2(u2.x), a1 = unpack_bf2(u2.y);
        float2 a2 = unpack_bf2(u2.z), a3 = unpack_bf2(u2.w);
        s0.x = fmaf(a0.x, n2, s0.x); s0.y = fmaf(a0.y, n2, s0.y);
        s0.z = fmaf(a1.x, n2, s0.z); s0.w = fmaf(a1.y, n2, s0.w);
        s1.x = fmaf(a2.x, n2, s1.x); s1.y = fmaf(a2.y, n2, s1.y);
        s1.z = fmaf(a3.x, n2, s1.z); s1.w = fmaf(a3.y, n2, s1.w);
    }
    {
        float2 a0 = unpack_bf2(u3.x), a1 = unpack_bf2(u3.y);
        float2 a2 = unpack_bf2(u3.z), a3 = unpack_bf2(u3.w);
        s0.x = fmaf(a0.x, n3, s0.x); s0.y = fmaf(a0.y, n3, s0.y);
        s0.z = fmaf(a1.x, n3, s0.z); s0.w = fmaf(a1.y, n3, s0.w);
        s1.x = fmaf(a2.x, n3, s1.x); s1.y = fmaf(a2.y, n3, s1.y);
        s1.z = fmaf(a3.x, n3, s1.z); s1.w = fmaf(a3.y, n3, s1.w);
    }
}

// ---- row accumulate: 4 u32 cols/thread, uint4 gathers, aligned uint4 csr
//      loads, 1-deep csr prefetch.
template <int W>
__device__ __forceinline__ void row_accum4(const unsigned* __restrict__ XWp,
                                           const unsigned* __restrict__ csr,
                                           int j, int end, int c,
                                           float4& s0, float4& s1) {
    while (j < end && (j & 3)) {
        edge1w<W>(XWp, csr[j++], c, s0, s1);
    }
    int nch = (end - j) >> 2;
    if (nch > 0) {
        uint4 p4 = *(const uint4*)(csr + j);
        for (int k = 1; k < nch; ++k) {
            uint4 p4n = *(const uint4*)(csr + j + (k << 2));  // prefetch next chunk
            edge4w<W>(XWp, p4, c, s0, s1);
            p4 = p4n;
        }
        edge4w<W>(XWp, p4, c, s0, s1);
        j += nch << 2;
    }
    for (; j < end; ++j) {
        edge1w<W>(XWp, csr[j], c, s0, s1);
    }
}

// ============================================================================
// FUSED layer-1 pull + layer-2 GEMM. Block = 64 nodes, 384 threads.
// Phase 1: 6 thr/node pull h1 rows (uint4 gathers) -> LDS h1 tile (bf16).
// Phase 2: barrier; 4 waves run the gemm2 MFMA (80 cols = W2|V2, K=48 pad 64)
//          reading A-frags from LDS; epilogue writes xW2p (*dinv) and agg2p.
// ============================================================================
__global__ __launch_bounds__(384) void pull_gemm2(
    const unsigned* __restrict__ XWp, const unsigned* __restrict__ csr,
    const int* __restrict__ rowBeg, const int* __restrict__ rowEnd,
    const unsigned* __restrict__ AGG1p, const float* __restrict__ W,
    const float* __restrict__ V, const float* __restrict__ b,
    const float* __restrict__ dinv, unsigned* __restrict__ XW2p,
    unsigned* __restrict__ AGG2p, int N) {
    __shared__ short sWT[80 * 64];   // [80 cols][64 k], k>=48 zero (10240 B)
    __shared__ short h1s[64 * 48];   // h1 tile, bf16 (6144 B)
    __shared__ float ep[64 * 80];    // epilogue staging (20480 B)
    int tid = threadIdx.x;
    int nb0 = (int)blockIdx.x * 64;

    // stage W2|V2 transposed (no sync needed until phase 2)
    for (int i = tid; i < 80 * 64; i += 384) {
        int c = i >> 6, k = i & 63;
        float v = 0.f;
        if (k < 48) v = (c < 40) ? W[k * 40 + c] : V[k * 40 + (c - 40)];
        sWT[i] = bfr(v);
    }

    // ---- phase 1: pull h1 for this block's 64 nodes ----
    int nl = tid / 6, c1 = tid - nl * 6;
    int n = nb0 + nl;
    int c = 4 * c1;
    if (n < N) {
        uint4 a = *(const uint4*)(AGG1p + n * 24 + c);
        float2 f0 = unpack_bf2(a.x), f1 = unpack_bf2(a.y);
        float2 f2 = unpack_bf2(a.z), f3 = unpack_bf2(a.w);
        float4 s0 = make_float4(f0.x, f0.y, f1.x, f1.y);
        float4 s1 = make_float4(f2.x, f2.y, f3.x, f3.y);
        row_accum4<24>(XWp, csr, rowBeg[n], rowEnd[n], c, s0, s1);
        uint4 o;
        o.x = pack_bf2(fmaxf(s0.x, 0.f), fmaxf(s0.y, 0.f));
        o.y = pack_bf2(fmaxf(s0.z, 0.f), fmaxf(s0.w, 0.f));
        o.z = pack_bf2(fmaxf(s1.x, 0.f), fmaxf(s1.y, 0.f));
        o.w = pack_bf2(fmaxf(s1.z, 0.f), fmaxf(s1.w, 0.f));
        *(uint4*)(h1s + nl * 48 + 8 * c1) = o;   // 16B-aligned LDS write
    } else {
        uint4 z = make_uint4(0, 0, 0, 0);
        *(uint4*)(h1s + nl * 48 + 8 * c1) = z;   // clean rows for MFMA
    }
    __syncthreads();

    // ---- phase 2: gemm2 MFMA from LDS (first 4 waves) ----
    if (tid < 256) {
        int lane = tid & 63, wv = tid >> 6;
        int m = lane & 15, quad = lane >> 4;
        bf16x8 a0 = *(const bf16x8*)(h1s + (wv * 16 + m) * 48 + quad * 8);
        bf16x8 a1;
        if (quad < 2) {
            a1 = *(const bf16x8*)(h1s + (wv * 16 + m) * 48 + 32 + quad * 8);
        } else {
            for (int j = 0; j < 8; ++j) a1[j] = 0;
        }
        f32x4 acc[5];
#pragma unroll
        for (int ct = 0; ct < 5; ++ct) acc[ct] = (f32x4){0.f, 0.f, 0.f, 0.f};
#pragma unroll
        for (int ct = 0; ct < 5; ++ct) {
            bf16x8 b0 = *(const bf16x8*)(sWT + (ct * 16 + m) * 64 + quad * 8);
            bf16x8 b1 = *(const bf16x8*)(sWT + (ct * 16 + m) * 64 + 32 + quad * 8);
            acc[ct] = __builtin_amdgcn_mfma_f32_16x16x32_bf16(a0, b0, acc[ct], 0, 0, 0);
            acc[ct] = __builtin_amdgcn_mfma_f32_16x16x32_bf16(a1, b1, acc[ct], 0, 0, 0);
        }
#pragma unroll
        for (int ct = 0; ct < 5; ++ct)
#pragma unroll
            for (int r = 0; r < 4; ++r)
                ep[(wv * 16 + quad * 4 + r) * 80 + ct * 16 + m] = acc[ct][r];
    }
    __syncthreads();
    for (int i = tid; i < 64 * 20; i += 384) {
        int r = i / 20, c2 = i - r * 20;
        int node = nb0 + r;
        if (node >= N) continue;
        float dv = dinv[node];
        float w0 = ep[r * 80 + 2 * c2], w1 = ep[r * 80 + 2 * c2 + 1];
        XW2p[node * 20 + c2] = pack_bf2(w0 * dv, w1 * dv);
        float v0 = ep[r * 80 + 40 + 2 * c2], v1 = ep[r * 80 + 40 + 2 * c2 + 1];
        float2 bb = ((const float2*)b)[c2];
        AGG2p[node * 20 + c2] = pack_bf2(v0 + bb.x, v1 + bb.y);
    }
}

// ---- layer-2 pull fused with log_softmax(relu(.)) --------------------------
// 5 threads/node, 4 u32 cols each (uint4 gathers); block 320 = 64 nodes.
__global__ __launch_bounds__(320) void pull_ls(const unsigned* __restrict__ XWp,
                                               const unsigned* __restrict__ csr,
                                               const int* __restrict__ rowBeg,
                                               const int* __restrict__ rowEnd,
                                               const unsigned* __restrict__ AGG2p,
                                               float* __restrict__ out, int N) {
    __shared__ float4 sbuf[64 * 10];
    __shared__ float sl[64];
    int tid = threadIdx.x;
    int nl = tid / 5, c1 = tid - nl * 5;
    int n = blockIdx.x * 64 + nl;
    int c = 4 * c1;
    float4 s0 = make_float4(0.f, 0.f, 0.f, 0.f);
    float4 s1 = make_float4(0.f, 0.f, 0.f, 0.f);
    if (n < N) {
        uint4 a = *(const uint4*)(AGG2p + n * 20 + c);
        float2 f0 = unpack_bf2(a.x), f1 = unpack_bf2(a.y);
        float2 f2 = unpack_bf2(a.z), f3 = unpack_bf2(a.w);
        s0 = make_float4(f0.x, f0.y, f1.x, f1.y);
        s1 = make_float4(f2.x, f2.y, f3.x, f3.y);
        row_accum4<20>(XWp, csr, rowBeg[n], rowEnd[n], c, s0, s1);
    }
    sbuf[(nl * 5 + c1) * 2] = s0;
    sbuf[(nl * 5 + c1) * 2 + 1] = s1;
    __syncthreads();
    if (tid < 64) {
        float m = 0.f;  // relu floor
        for (int k = 0; k < 10; ++k) {
            float4 v = sbuf[tid * 10 + k];
            m = fmaxf(m, fmaxf(fmaxf(v.x, v.y), fmaxf(v.z, v.w)));
        }
        float sum = 0.f;
        for (int k = 0; k < 10; ++k) {
            float4 v = sbuf[tid * 10 + k];
            sum += expf(fmaxf(v.x, 0.f) - m) + expf(fmaxf(v.y, 0.f) - m) +
                   expf(fmaxf(v.z, 0.f) - m) + expf(fmaxf(v.w, 0.f) - m);
        }
        sl[tid] = m + logf(sum);
    }
    __syncthreads();
    if (n < N) {
        float l = sl[nl];
        float4* op = (float4*)(out + (size_t)n * 40 + 8 * c1);
        op[0] = make_float4(fmaxf(s0.x, 0.f) - l, fmaxf(s0.y, 0.f) - l,
                            fmaxf(s0.z, 0.f) - l, fmaxf(s0.w, 0.f) - l);
        op[1] = make_float4(fmaxf(s1.x, 0.f) - l, fmaxf(s1.y, 0.f) - l,
                            fmaxf(s1.z, 0.f) - l, fmaxf(s1.w, 0.f) - l);
    }
}

extern "C" void kernel_launch(void* const* d_in, const int* in_sizes, int n_in,
                              void* d_out, int out_size, void* d_ws, size_t ws_size,
                              hipStream_t stream) {
    const float* x  = (const float*)d_in[0];
    const int*   ei = (const int*)d_in[1];
    const float* ew = (const float*)d_in[2];
    const float* W1 = (const float*)d_in[3];
    const float* V1 = (const float*)d_in[4];
    const float* b1 = (const float*)d_in[5];
    const float* W2 = (const float*)d_in[6];
    const float* V2 = (const float*)d_in[7];
    const float* b2 = (const float*)d_in[8];
    float* out = (float*)d_out;

    const int N = in_sizes[0] / F_IN;
    const int E = in_sizes[2];
    const int* src = ei;
    const int* dst = ei + E;

    char* ws = (char*)d_ws;
    size_t off = 0;
    auto carve = [&](size_t bytes) {
        void* p = ws + off;
        off = (off + bytes + 255) & ~size_t(255);
        return p;
    };
    int*      binCursor = (int*)carve(256 * 4);
    int*      rowBeg    = (int*)carve((size_t)N * 4);
    int*      rowEnd    = (int*)carve((size_t)N * 4);
    float*    dinv      = (float*)carve((size_t)N * 4);
    int2*     binned    = (int2*)carve((size_t)256 * BIN_CAP * 8);
    unsigned* csr       = (unsigned*)carve((size_t)256 * BIN_CAP * 4);
    unsigned* xW1p      = (unsigned*)carve((size_t)N * 24 * 4);   // bf16x2 flat
    unsigned* agg1p     = (unsigned*)carve((size_t)N * 24 * 4);   // bf16x2 V1-part
    unsigned* xW2p      = (unsigned*)carve((size_t)N * 20 * 4);
    unsigned* agg2p     = (unsigned*)carve((size_t)N * 20 * 4);   // bf16x2 V2-part

    const int B = 256;
    auto cdiv = [](long long a, long long b) { return (int)((a + b - 1) / b); };
    const int nSc = cdiv(E, CHUNK);
    const int nBins = (N + (1 << BIN_SHIFT) - 1) >> BIN_SHIFT;
    const int nGemmBlocks = cdiv(N, 64);

    init_cursor<<<1, 256, 0, stream>>>(binCursor);
    gemm1_binscatter<<<nSc + nGemmBlocks, B, 0, stream>>>(
        x, W1, V1, b1, xW1p, agg1p, N, src, dst, ew, binCursor, binned, E, nSc);
    build_csr<<<nBins, 512, 0, stream>>>(binned, binCursor, rowBeg, rowEnd,
                                         dinv, csr, xW1p, N);

    pull_gemm2<<<nGemmBlocks, 384, 0, stream>>>(xW1p, csr, rowBeg, rowEnd,
                                                agg1p, W2, V2, b2, dinv,
                                                xW2p, agg2p, N);

    pull_ls<<<cdiv(N, 64), 320, 0, stream>>>(xW2p, csr, rowBeg, rowEnd,
                                             agg2p, out, N);
}